// Round 6
// baseline (1314.157 us; speedup 1.0000x reference)
//
#include <hip/hip_runtime.h>

#define N_NODES 50000
#define N_EDGES 800000
#define DD 128
#define HH 128
#define LL 4
#define AHH 16
#define LN_EPS 1e-5f
#define NCOLS 432   // 128 S | 128 P1 | 128 Pd | 16 SA | 16 P1A | 16 PdA
#define SCAN_B 512
#define SCAN_NB ((N_NODES + SCAN_B - 1) / SCAN_B)

typedef unsigned short u16;
typedef unsigned int u32;
typedef __attribute__((ext_vector_type(8))) short short8;
typedef __attribute__((ext_vector_type(4))) float f32x4;

__device__ __forceinline__ float bf2f(u16 h){
  u32 u = ((u32)h) << 16;
  return __builtin_bit_cast(float, u);
}
__device__ __forceinline__ float bflo(u32 v){ return __builtin_bit_cast(float, v << 16); }
__device__ __forceinline__ float bfhi(u32 v){ return __builtin_bit_cast(float, v & 0xffff0000u); }
__device__ __forceinline__ u16 f2bf(float x){
  u32 u = __builtin_bit_cast(u32, x);
  u += 0x7fffu + ((u >> 16) & 1u);
  return (u16)(u >> 16);
}

// ---------------- sentinel (workspace too small even for fused path) ----------------
__global__ void k_fail(float* out){
  int i = blockIdx.x*256 + threadIdx.x;
  if (i < N_NODES*2) out[i] = 1.0e6f;
}

// ---------------- f32 -> bf16 conversion of node features ----------------
__global__ void k_cvt(const float* __restrict__ X, u16* __restrict__ Xb){
  int i = blockIdx.x*256 + threadIdx.x;
  if (i < N_NODES*DD) Xb[i] = f2bf(X[i]);
}

// ---------------- CSR build ----------------
__global__ void k_hist(const int* __restrict__ ei, int* degO, int* degI){
  int e = blockIdx.x*256 + threadIdx.x;
  if (e >= N_EDGES) return;
  atomicAdd(&degO[ei[N_EDGES + e]], 1);  // tgt histogram (outgoing view)
  atomicAdd(&degI[ei[e]], 1);            // src histogram (incoming view)
}

// 3-phase parallel exclusive scan
__global__ __launch_bounds__(SCAN_B) void k_scan1(const int* __restrict__ degO,
                                                  const int* __restrict__ degI, int* bsum){
  int b = blockIdx.x, t = threadIdx.x;
  const int* deg = blockIdx.y ? degI : degO;
  int i = b*SCAN_B + t;
  int v = (i < N_NODES) ? deg[i] : 0;
  #pragma unroll
  for (int m = 1; m < 64; m <<= 1) v += __shfl_xor(v, m);
  __shared__ int ws[SCAN_B/64];
  if ((t & 63) == 0) ws[t >> 6] = v;
  __syncthreads();
  if (t == 0){
    int s = 0;
    for (int w = 0; w < SCAN_B/64; ++w) s += ws[w];
    bsum[blockIdx.y*SCAN_NB + b] = s;
  }
}
__global__ void k_scan2(int* bsum, int* offO, int* offI){
  if (threadIdx.x == 0){
    int run = 0;
    for (int i = 0; i < SCAN_NB; ++i){ int v = bsum[i]; bsum[i] = run; run += v; }
    offO[N_NODES] = run;
    run = 0;
    for (int i = 0; i < SCAN_NB; ++i){ int v = bsum[SCAN_NB+i]; bsum[SCAN_NB+i] = run; run += v; }
    offI[N_NODES] = run;
  }
}
__global__ __launch_bounds__(SCAN_B) void k_scan3(const int* __restrict__ degO,
                                                  const int* __restrict__ degI,
                                                  const int* __restrict__ bsum,
                                                  int* offO, int* offI){
  int b = blockIdx.x, t = threadIdx.x, lane = t & 63, w = t >> 6;
  const int* deg = blockIdx.y ? degI : degO;
  int* off = blockIdx.y ? offI : offO;
  int i = b*SCAN_B + t;
  int v = (i < N_NODES) ? deg[i] : 0;
  int x = v;
  #pragma unroll
  for (int m = 1; m < 64; m <<= 1){ int tt = __shfl_up(x, m); if (lane >= m) x += tt; }
  __shared__ int ws[SCAN_B/64];
  if (lane == 63) ws[w] = x;
  __syncthreads();
  int woff = 0;
  for (int k = 0; k < w; ++k) woff += ws[k];
  if (i < N_NODES) off[i] = bsum[blockIdx.y*SCAN_NB + b] + woff + x - v;
}

__global__ void k_scatter(const int* __restrict__ ei, const int* __restrict__ offO,
                          const int* __restrict__ offI, int* cursO, int* cursI,
                          int* csrO, int* csrI){
  int e = blockIdx.x*256 + threadIdx.x;
  if (e >= N_EDGES) return;
  int s = ei[e], t = ei[N_EDGES + e];
  int p = atomicAdd(&cursO[t], 1); csrO[offO[t] + p] = s;
  int q = atomicAdd(&cursI[s], 1); csrI[offI[s] + q] = t;
}

// ---------------- weight packing (f32 sources -> bf16 WT) ----------------
__global__ void k_pack_wt(const float* __restrict__ Wself, const float* __restrict__ Wctx,
                          const float* __restrict__ A1, u16* __restrict__ WT){
  int idx = blockIdx.x*256 + threadIdx.x;
  if (idx >= LL*NCOLS*DD) return;
  int k = idx & 127;
  int j = (idx >> 7) % NCOLS;
  int l = idx / (NCOLS*DD);
  const float* Ws = Wself + (size_t)l*DD*HH;
  const float* Wc = Wctx + (size_t)l*2*DD*HH;
  const float* A  = A1 + (size_t)l*HH*AHH;
  float v = 0.f;
  if (j < 128) v = Ws[k*HH + j];
  else if (j < 256) v = Wc[k*HH + (j-128)];
  else if (j < 384) v = Wc[(128+k)*HH + (j-256)] - Wc[k*HH + (j-256)];
  else if (j < 400){ int a = j-384; for (int h=0; h<HH; ++h) v += Ws[k*HH+h] * A[h*AHH+a]; }
  else if (j < 416){ int a = j-400; for (int h=0; h<HH; ++h) v += Wc[k*HH+h] * A[h*AHH+a]; }
  else { int a = j-416; for (int h=0; h<HH; ++h) v += (Wc[(128+k)*HH+h] - Wc[k*HH+h]) * A[h*AHH+a]; }
  WT[((size_t)l*NCOLS + j)*DD + k] = f2bf(v);
}

__global__ void k_pack_bias(const float* __restrict__ bs, const float* __restrict__ bc,
                            const float* __restrict__ A1, float* bsA, float* bcA){
  int i = threadIdx.x;
  if (i >= LL*2*AHH) return;
  int l = i >> 5, which = (i >> 4) & 1, a = i & 15;
  const float* b = which ? (bc + l*HH) : (bs + l*HH);
  const float* A = A1 + (size_t)l*HH*AHH;
  float v = 0.f;
  for (int h = 0; h < HH; ++h) v += b[h] * A[h*AHH + a];
  (which ? bcA : bsA)[l*AHH + a] = v;
}

// ---------------- fused GEMM: [N,128] @ [128,432] via MFMA ----------------
struct GemmOut { u16 *S, *P1, *Pd, *SA, *P1A, *PdA; };

__global__ __launch_bounds__(256) void k_gemm(const u16* __restrict__ X,
                                              const u16* __restrict__ WT, GemmOut o){
  int wid = (blockIdx.x * 256 + threadIdx.x) >> 6;
  int lane = threadIdx.x & 63;
  int m0 = wid * 16;
  if (m0 >= N_NODES) return;
  int l15 = lane & 15, quad = lane >> 4;
  f32x4 acc[27];
  #pragma unroll
  for (int j = 0; j < 27; ++j) acc[j] = (f32x4){0.f,0.f,0.f,0.f};
  const u16* xr = X + (size_t)(m0 + l15)*DD + quad*8;
  const u16* wb = WT + (size_t)l15*DD + quad*8;
  #pragma unroll
  for (int ks = 0; ks < 4; ++ks){
    short8 a = *(const short8*)(xr + ks*32);
    #pragma unroll
    for (int j = 0; j < 27; ++j){
      short8 b = *(const short8*)(wb + (size_t)j*16*DD + ks*32);
      acc[j] = __builtin_amdgcn_mfma_f32_16x16x32_bf16(a, b, acc[j], 0, 0, 0);
    }
  }
  #pragma unroll
  for (int j = 0; j < 27; ++j){
    int col = j*16 + l15;
    #pragma unroll
    for (int r = 0; r < 4; ++r){
      int row = m0 + quad*4 + r;
      u16 hv = f2bf(acc[j][r]);
      if (col < 128)      o.S  [(size_t)row*128 + col]       = hv;
      else if (col < 256) o.P1 [(size_t)row*128 + col - 128] = hv;
      else if (col < 384) o.Pd [(size_t)row*128 + col - 256] = hv;
      else if (col < 400) o.SA [(size_t)row*16  + col - 384] = hv;
      else if (col < 416) o.P1A[(size_t)row*16  + col - 400] = hv;
      else                o.PdA[(size_t)row*16  + col - 416] = hv;
    }
  }
}

// ---------------- chunked gather: blockIdx.y = feature chunk (32 feats, 3.2 MB window) ----------------
// Temporal L2 blocking: HW dispatches x-fastest, so chunk phases are device-wide sequential.
__global__ __launch_bounds__(256) void k_gather(const u16* __restrict__ Pd,
    const int* __restrict__ offO, const int* __restrict__ offI,
    const int* __restrict__ csrO, const int* __restrict__ csrI,
    float* __restrict__ Agg /* [node][2][128] f32 */){
  int n = blockIdx.x*4 + (threadIdx.x >> 6);
  int c = blockIdx.y;
  int lane = threadIdx.x & 63;
  int l16 = lane & 15, g = lane >> 4;
  const u16* PdC = Pd + c*32 + 2*l16;   // + nb*128 per edge
  #pragma unroll
  for (int dir = 0; dir < 2; ++dir){
    const int* off = dir ? offI : offO;
    const int* csr = dir ? csrI : csrO;
    int beg = off[n], end = off[n+1];
    float a0 = 0.f, a1 = 0.f, b0 = 0.f, b1 = 0.f;
    int e = beg + g;
    for (; e + 4 < end; e += 8){
      int nb0 = csr[e], nb1 = csr[e+4];
      u32 v0 = *(const u32*)(PdC + (size_t)nb0*128);
      u32 v1 = *(const u32*)(PdC + (size_t)nb1*128);
      a0 += bflo(v0); a1 += bfhi(v0);
      b0 += bflo(v1); b1 += bfhi(v1);
    }
    if (e < end){
      u32 v = *(const u32*)(PdC + (size_t)csr[e]*128);
      a0 += bflo(v); a1 += bfhi(v);
    }
    a0 += b0; a1 += b1;
    a0 += __shfl_xor(a0, 16); a0 += __shfl_xor(a0, 32);
    a1 += __shfl_xor(a1, 16); a1 += __shfl_xor(a1, 32);
    if (g == 0)
      *(float2*)(Agg + ((size_t)n*2 + dir)*128 + c*32 + 2*l16) = make_float2(a0, a1);
  }
}

// ------- epilogue: PdA gather + attention + LN + residual + classifier-accumulate -------
__global__ __launch_bounds__(256) void k_epi(int l,
  const u16* __restrict__ S, const u16* __restrict__ P1,
  const u16* __restrict__ SA, const u16* __restrict__ P1A, const u16* __restrict__ PdA,
  const float* __restrict__ Agg,
  const int* __restrict__ offO, const int* __restrict__ offI,
  const int* __restrict__ csrO, const int* __restrict__ csrI,
  const float* __restrict__ b_self, const float* __restrict__ b_ctx,
  const float* __restrict__ bsA, const float* __restrict__ bcA,
  const float* __restrict__ att_b1, const float* __restrict__ att_w2,
  const float* __restrict__ gamma, const float* __restrict__ beta,
  const float* __restrict__ flog,
  float* __restrict__ xf, u16* __restrict__ xb16,
  const float* __restrict__ clsW, const float* __restrict__ clsB,
  float* __restrict__ out)
{
  int n = (blockIdx.x * 256 + threadIdx.x) >> 6;
  int lane = threadIdx.x & 63;
  int f0 = lane * 2;
  int a16 = lane & 15, g = lane >> 4;

  int begO = offO[n], endO = offO[n+1];
  int begI = offI[n], endI = offI[n+1];

  // PdA gathers (1.6 MB, L2-resident): 4 edges per iteration via the 16-lane groups
  float aoa = 0.f, aia = 0.f;
  for (int e2 = begO + g; e2 < endO; e2 += 4)
    aoa += bf2f(PdA[(size_t)csrO[e2]*16 + a16]);
  for (int e2 = begI + g; e2 < endI; e2 += 4)
    aia += bf2f(PdA[(size_t)csrI[e2]*16 + a16]);
  aoa += __shfl_xor(aoa, 16); aoa += __shfl_xor(aoa, 32);
  aia += __shfl_xor(aia, 16); aia += __shfl_xor(aia, 32);

  float2 ao = *(const float2*)(Agg + ((size_t)n*2 + 0)*128 + f0);
  float2 ai = *(const float2*)(Agg + ((size_t)n*2 + 1)*128 + f0);
  float dO = (float)(endO - begO), dI = (float)(endI - begI);

  u32 sv = *(const u32*)(S  + (size_t)n*128 + f0);
  u32 pv = *(const u32*)(P1 + (size_t)n*128 + f0);
  float2 bsv = *(const float2*)(b_self + l*128 + f0);
  float2 bcv = *(const float2*)(b_ctx  + l*128 + f0);
  float p10 = bflo(pv), p11 = bfhi(pv);
  float mv00 = bflo(sv) + bsv.x;
  float mv01 = bfhi(sv) + bsv.y;
  float mv10 = dO*p10 + ao.x + bcv.x, mv11 = dO*p11 + ao.y + bcv.y;
  float mv20 = dI*p10 + ai.x + bcv.x, mv21 = dI*p11 + ai.y + bcv.y;

  // attention: lanes [v*16 + a], v<3 compute tanh(t + b1)*w2, reduce over a
  int a = a16, v = g;
  float u = 0.f;
  if (v < 3){
    float t;
    if (v == 0)      t = bf2f(SA[(size_t)n*16 + a]) + bsA[l*16 + a];
    else if (v == 1) t = dO*bf2f(P1A[(size_t)n*16 + a]) + aoa + bcA[l*16 + a];
    else             t = dI*bf2f(P1A[(size_t)n*16 + a]) + aia + bcA[l*16 + a];
    u = tanhf(t + att_b1[l*16 + a]) * att_w2[l*16 + a];
  }
  u += __shfl_xor(u, 1); u += __shfl_xor(u, 2);
  u += __shfl_xor(u, 4); u += __shfl_xor(u, 8);
  float s0 = __shfl(u, 0), s1 = __shfl(u, 16), s2 = __shfl(u, 32);
  float mx = fmaxf(s0, fmaxf(s1, s2));
  float e0 = __expf(s0-mx), e1 = __expf(s1-mx), e2 = __expf(s2-mx);
  float inv = 1.f / (e0 + e1 + e2);
  float w0 = e0*inv, w1 = e1*inv, w2v = e2*inv;
  float h0 = w0*mv00 + w1*mv10 + w2v*mv20;
  float h1 = w0*mv01 + w1*mv11 + w2v*mv21;

  // layer norm over 128
  float sum = h0 + h1, sq = h0*h0 + h1*h1;
  #pragma unroll
  for (int m = 1; m < 64; m <<= 1){ sum += __shfl_xor(sum, m); sq += __shfl_xor(sq, m); }
  float mu = sum * (1.f/128.f);
  float var = sq * (1.f/128.f) - mu*mu;
  float rs = rsqrtf(var + LN_EPS);
  float2 gv = *(const float2*)(gamma + l*128 + f0);
  float2 bv = *(const float2*)(beta  + l*128 + f0);
  float y0 = fmaxf((h0 - mu)*rs*gv.x + bv.x, 0.f);
  float y1 = fmaxf((h1 - mu)*rs*gv.y + bv.y, 0.f);
  float xn0 = y0, xn1 = y1;
  if (l > 0){
    float2 xv = *(const float2*)(xf + (size_t)n*128 + f0);
    xn0 += xv.x; xn1 += xv.y;
  }
  *(float2*)(xf + (size_t)n*128 + f0) = make_float2(xn0, xn1);
  *(u32*)(xb16 + (size_t)n*128 + f0) = (u32)f2bf(xn0) | ((u32)f2bf(xn1) << 16);

  float g0 = flog[0], g1 = flog[1], g2 = flog[2], g3 = flog[3];
  float gm = fmaxf(fmaxf(g0,g1), fmaxf(g2,g3));
  float q0 = __expf(g0-gm), q1 = __expf(g1-gm), q2 = __expf(g2-gm), q3 = __expf(g3-gm);
  float fwl = (l==0?q0 : l==1?q1 : l==2?q2 : q3) / (q0+q1+q2+q3);

  float4 w = *(const float4*)(clsW + lane*4);
  float o0 = xn0*w.x + xn1*w.z;
  float o1 = xn0*w.y + xn1*w.w;
  #pragma unroll
  for (int m = 1; m < 64; m <<= 1){ o0 += __shfl_xor(o0, m); o1 += __shfl_xor(o1, m); }
  if (lane == 0){
    float2* op = (float2*)(out + (size_t)n*2);
    float2 prev = (l > 0) ? *op : make_float2(0.f, 0.f);
    float r0 = prev.x + fwl*o0, r1 = prev.y + fwl*o1;
    if (l == LL-1){ r0 += clsB[0]; r1 += clsB[1]; }
    *op = make_float2(r0, r1);
  }
}

// ------- fallback fused kernel (R5 path) used when workspace can't hold Agg -------
__global__ __launch_bounds__(256) void k_aggepi(int l,
  const u16* __restrict__ S, const u16* __restrict__ P1,
  const u16* __restrict__ Pd, const u16* __restrict__ SA,
  const u16* __restrict__ P1A, const u16* __restrict__ PdA,
  const int* __restrict__ offO, const int* __restrict__ offI,
  const int* __restrict__ csrO, const int* __restrict__ csrI,
  const float* __restrict__ b_self, const float* __restrict__ b_ctx,
  const float* __restrict__ bsA, const float* __restrict__ bcA,
  const float* __restrict__ att_b1, const float* __restrict__ att_w2,
  const float* __restrict__ gamma, const float* __restrict__ beta,
  const float* __restrict__ flog,
  float* __restrict__ xf, u16* __restrict__ xb16,
  const float* __restrict__ clsW, const float* __restrict__ clsB,
  float* __restrict__ out)
{
  int n = (blockIdx.x * 256 + threadIdx.x) >> 6;
  int lane = threadIdx.x & 63;
  int f0 = lane * 2;
  const u16* PdF = Pd + f0;
  int begO = offO[n], endO = offO[n+1];
  int begI = offI[n], endI = offI[n+1];
  float o00=0.f,o01=0.f,o10=0.f,o11=0.f;
  float i00=0.f,i01=0.f,i10=0.f,i11=0.f;
  int eO = begO, eI = begI;
  for (; eO + 2 <= endO && eI + 2 <= endI; eO += 2, eI += 2){
    u32 a0 = *(const u32*)(PdF + (size_t)csrO[eO]*128);
    u32 a1 = *(const u32*)(PdF + (size_t)csrO[eO+1]*128);
    u32 b0 = *(const u32*)(PdF + (size_t)csrI[eI]*128);
    u32 b1 = *(const u32*)(PdF + (size_t)csrI[eI+1]*128);
    o00 += bflo(a0); o01 += bfhi(a0); o10 += bflo(a1); o11 += bfhi(a1);
    i00 += bflo(b0); i01 += bfhi(b0); i10 += bflo(b1); i11 += bfhi(b1);
  }
  for (; eO < endO; ++eO){ u32 v = *(const u32*)(PdF + (size_t)csrO[eO]*128); o00 += bflo(v); o01 += bfhi(v); }
  for (; eI < endI; ++eI){ u32 v = *(const u32*)(PdF + (size_t)csrI[eI]*128); i00 += bflo(v); i01 += bfhi(v); }
  float ao0 = o00+o10, ao1 = o01+o11, ai0 = i00+i10, ai1 = i01+i11;
  int a16 = lane & 15, g = lane >> 4;
  float aoa = 0.f, aia = 0.f;
  for (int e2 = begO + g; e2 < endO; e2 += 4) aoa += bf2f(PdA[(size_t)csrO[e2]*16 + a16]);
  for (int e2 = begI + g; e2 < endI; e2 += 4) aia += bf2f(PdA[(size_t)csrI[e2]*16 + a16]);
  aoa += __shfl_xor(aoa, 16); aoa += __shfl_xor(aoa, 32);
  aia += __shfl_xor(aia, 16); aia += __shfl_xor(aia, 32);
  float dO = (float)(endO - begO), dI = (float)(endI - begI);
  u32 sv = *(const u32*)(S  + (size_t)n*128 + f0);
  u32 pv = *(const u32*)(P1 + (size_t)n*128 + f0);
  float2 bsv = *(const float2*)(b_self + l*128 + f0);
  float2 bcv = *(const float2*)(b_ctx  + l*128 + f0);
  float p10 = bflo(pv), p11 = bfhi(pv);
  float mv00 = bflo(sv) + bsv.x;
  float mv01 = bfhi(sv) + bsv.y;
  float mv10 = dO*p10 + ao0 + bcv.x, mv11 = dO*p11 + ao1 + bcv.y;
  float mv20 = dI*p10 + ai0 + bcv.x, mv21 = dI*p11 + ai1 + bcv.y;
  int a = a16, v = g;
  float u = 0.f;
  if (v < 3){
    float t;
    if (v == 0)      t = bf2f(SA[(size_t)n*16 + a]) + bsA[l*16 + a];
    else if (v == 1) t = dO*bf2f(P1A[(size_t)n*16 + a]) + aoa + bcA[l*16 + a];
    else             t = dI*bf2f(P1A[(size_t)n*16 + a]) + aia + bcA[l*16 + a];
    u = tanhf(t + att_b1[l*16 + a]) * att_w2[l*16 + a];
  }
  u += __shfl_xor(u, 1); u += __shfl_xor(u, 2);
  u += __shfl_xor(u, 4); u += __shfl_xor(u, 8);
  float s0 = __shfl(u, 0), s1 = __shfl(u, 16), s2 = __shfl(u, 32);
  float mx = fmaxf(s0, fmaxf(s1, s2));
  float e0 = __expf(s0-mx), e1 = __expf(s1-mx), e2 = __expf(s2-mx);
  float inv = 1.f / (e0 + e1 + e2);
  float w0 = e0*inv, w1 = e1*inv, w2v = e2*inv;
  float h0 = w0*mv00 + w1*mv10 + w2v*mv20;
  float h1 = w0*mv01 + w1*mv11 + w2v*mv21;
  float sum = h0 + h1, sq = h0*h0 + h1*h1;
  #pragma unroll
  for (int m = 1; m < 64; m <<= 1){ sum += __shfl_xor(sum, m); sq += __shfl_xor(sq, m); }
  float mu = sum * (1.f/128.f);
  float var = sq * (1.f/128.f) - mu*mu;
  float rs = rsqrtf(var + LN_EPS);
  float2 gv = *(const float2*)(gamma + l*128 + f0);
  float2 bv = *(const float2*)(beta  + l*128 + f0);
  float y0 = fmaxf((h0 - mu)*rs*gv.x + bv.x, 0.f);
  float y1 = fmaxf((h1 - mu)*rs*gv.y + bv.y, 0.f);
  float xn0 = y0, xn1 = y1;
  if (l > 0){
    float2 xv = *(const float2*)(xf + (size_t)n*128 + f0);
    xn0 += xv.x; xn1 += xv.y;
  }
  *(float2*)(xf + (size_t)n*128 + f0) = make_float2(xn0, xn1);
  *(u32*)(xb16 + (size_t)n*128 + f0) = (u32)f2bf(xn0) | ((u32)f2bf(xn1) << 16);
  float g0 = flog[0], g1 = flog[1], g2 = flog[2], g3 = flog[3];
  float gm = fmaxf(fmaxf(g0,g1), fmaxf(g2,g3));
  float q0 = __expf(g0-gm), q1 = __expf(g1-gm), q2 = __expf(g2-gm), q3 = __expf(g3-gm);
  float fwl = (l==0?q0 : l==1?q1 : l==2?q2 : q3) / (q0+q1+q2+q3);
  float4 w = *(const float4*)(clsW + lane*4);
  float o0 = xn0*w.x + xn1*w.z;
  float o1 = xn0*w.y + xn1*w.w;
  #pragma unroll
  for (int m = 1; m < 64; m <<= 1){ o0 += __shfl_xor(o0, m); o1 += __shfl_xor(o1, m); }
  if (lane == 0){
    float2* op = (float2*)(out + (size_t)n*2);
    float2 prev = (l > 0) ? *op : make_float2(0.f, 0.f);
    float r0 = prev.x + fwl*o0, r1 = prev.y + fwl*o1;
    if (l == LL-1){ r0 += clsB[0]; r1 += clsB[1]; }
    *op = make_float2(r0, r1);
  }
}

extern "C" void kernel_launch(void* const* d_in, const int* in_sizes, int n_in,
                              void* d_out, int out_size, void* d_ws, size_t ws_size,
                              hipStream_t stream){
  const float* X0    = (const float*)d_in[0];
  const int*   EI    = (const int*)d_in[1];
  const float* Wself = (const float*)d_in[2];
  const float* bs    = (const float*)d_in[3];
  const float* Wctx  = (const float*)d_in[4];
  const float* bc    = (const float*)d_in[5];
  const float* A1    = (const float*)d_in[6];
  const float* ab1   = (const float*)d_in[7];
  const float* aw2   = (const float*)d_in[8];
  const float* gam   = (const float*)d_in[9];
  const float* bet   = (const float*)d_in[10];
  const float* flog  = (const float*)d_in[11];
  const float* clsW  = (const float*)d_in[12];
  const float* clsB  = (const float*)d_in[13];
  float* out = (float*)d_out;

  char* wsp = (char*)d_ws;
  size_t o = 0;
  auto alloc = [&](size_t b)->char*{ char* p = wsp + o; o = (o + b + 255) & ~(size_t)255; return p; };
  u16*  xb16  = (u16*) alloc((size_t)N_NODES*128*2);
  float* xf   = (float*)alloc((size_t)N_NODES*128*4);
  u16*  S     = (u16*) alloc((size_t)N_NODES*128*2);
  u16*  P1    = (u16*) alloc((size_t)N_NODES*128*2);
  u16*  Pd    = (u16*) alloc((size_t)N_NODES*128*2);
  u16*  SAb   = (u16*) alloc((size_t)N_NODES*16*2);
  u16*  P1A   = (u16*) alloc((size_t)N_NODES*16*2);
  u16*  PdA   = (u16*) alloc((size_t)N_NODES*16*2);
  u16*  WT    = (u16*) alloc((size_t)LL*NCOLS*128*2);
  float* bsA  = (float*)alloc(LL*16*4);
  float* bcA  = (float*)alloc(LL*16*4);
  int* bsum   = (int*) alloc((size_t)2*SCAN_NB*4);
  int* degO   = (int*) alloc((size_t)N_NODES*4);
  int* degI   = (int*) alloc((size_t)N_NODES*4);
  int* cursO  = (int*) alloc((size_t)N_NODES*4);
  int* cursI  = (int*) alloc((size_t)N_NODES*4);
  int* offO   = (int*) alloc((size_t)(N_NODES+1)*4);
  int* offI   = (int*) alloc((size_t)(N_NODES+1)*4);
  int* csrO   = (int*) alloc((size_t)N_EDGES*4);
  int* csrI   = (int*) alloc((size_t)N_EDGES*4);
  size_t base_need = o;
  float* Agg = (float*)alloc((size_t)N_NODES*2*128*4);   // split-path only
  int split = (ws_size >= o) ? 1 : 0;

  if (ws_size < base_need){
    k_fail<<<(N_NODES*2+255)/256, 256, 0, stream>>>(out);
    return;
  }

  hipMemsetAsync(degO, 0, (size_t)((char*)offO - (char*)degO), stream);

  k_cvt<<<(N_NODES*DD+255)/256, 256, 0, stream>>>(X0, xb16);
  k_hist<<<(N_EDGES+255)/256, 256, 0, stream>>>(EI, degO, degI);
  k_scan1<<<dim3(SCAN_NB,2), SCAN_B, 0, stream>>>(degO, degI, bsum);
  k_scan2<<<1, 64, 0, stream>>>(bsum, offO, offI);
  k_scan3<<<dim3(SCAN_NB,2), SCAN_B, 0, stream>>>(degO, degI, bsum, offO, offI);
  k_scatter<<<(N_EDGES+255)/256, 256, 0, stream>>>(EI, offO, offI, cursO, cursI, csrO, csrI);
  k_pack_wt<<<(LL*NCOLS*128+255)/256, 256, 0, stream>>>(Wself, Wctx, A1, WT);
  k_pack_bias<<<1, 128, 0, stream>>>(bs, bc, A1, bsA, bcA);

  GemmOut go{S, P1, Pd, SAb, P1A, PdA};
  const int gemm_blocks = ((N_NODES/16) + 3) / 4;
  for (int l = 0; l < LL; ++l){
    k_gemm<<<gemm_blocks, 256, 0, stream>>>(xb16, WT + (size_t)l*NCOLS*128, go);
    if (split){
      k_gather<<<dim3(N_NODES/4, 4), 256, 0, stream>>>(Pd, offO, offI, csrO, csrI, Agg);
      k_epi<<<N_NODES/4, 256, 0, stream>>>(l, S, P1, SAb, P1A, PdA, Agg,
                                           offO, offI, csrO, csrI,
                                           bs, bc, bsA, bcA, ab1, aw2,
                                           gam, bet, flog, xf, xb16,
                                           clsW, clsB, out);
    } else {
      k_aggepi<<<N_NODES/4, 256, 0, stream>>>(l, S, P1, Pd, SAb, P1A, PdA,
                                              offO, offI, csrO, csrI,
                                              bs, bc, bsA, bcA, ab1, aw2,
                                              gam, bet, flog, xf, xb16,
                                              clsW, clsB, out);
    }
  }
}

// Round 8
// 1228.235 us; speedup vs baseline: 1.0700x; 1.0700x over previous
//
#include <hip/hip_runtime.h>

#define N_NODES 50000
#define N_EDGES 800000
#define DD 128
#define HH 128
#define LL 4
#define AHH 16
#define LN_EPS 1e-5f
#define NCOLS 432   // 128 S | 128 P1 | 128 Pd | 16 SA | 16 P1A | 16 PdA
#define SCAN_B 512
#define SCAN_NB ((N_NODES + SCAN_B - 1) / SCAN_B)
#define WTPAD 136   // LDS row pitch (u16): 272B -> 4-bank shift/row, conflict-free b128 reads

typedef unsigned short u16;
typedef unsigned int u32;
typedef __attribute__((ext_vector_type(8))) short short8;
typedef __attribute__((ext_vector_type(4))) float f32x4;
typedef __attribute__((ext_vector_type(2))) float f32x2;

__device__ __forceinline__ float bf2f(u16 h){
  u32 u = ((u32)h) << 16;
  return __builtin_bit_cast(float, u);
}
__device__ __forceinline__ float bflo(u32 v){ return __builtin_bit_cast(float, v << 16); }
__device__ __forceinline__ float bfhi(u32 v){ return __builtin_bit_cast(float, v & 0xffff0000u); }
__device__ __forceinline__ u16 f2bf(float x){
  u32 u = __builtin_bit_cast(u32, x);
  u += 0x7fffu + ((u >> 16) & 1u);
  return (u16)(u >> 16);
}

// ---------------- sentinel (workspace too small even for fused path) ----------------
__global__ void k_fail(float* out){
  int i = blockIdx.x*256 + threadIdx.x;
  if (i < N_NODES*2) out[i] = 1.0e6f;
}

// ---------------- f32 -> bf16 conversion of node features ----------------
__global__ void k_cvt(const float* __restrict__ X, u16* __restrict__ Xb){
  int i = blockIdx.x*256 + threadIdx.x;
  if (i < N_NODES*DD) Xb[i] = f2bf(X[i]);
}

// ---------------- CSR build ----------------
__global__ void k_hist(const int* __restrict__ ei, int* degO, int* degI){
  int e = blockIdx.x*256 + threadIdx.x;
  if (e >= N_EDGES) return;
  atomicAdd(&degO[ei[N_EDGES + e]], 1);  // tgt histogram (outgoing view)
  atomicAdd(&degI[ei[e]], 1);            // src histogram (incoming view)
}

// 3-phase parallel exclusive scan
__global__ __launch_bounds__(SCAN_B) void k_scan1(const int* __restrict__ degO,
                                                  const int* __restrict__ degI, int* bsum){
  int b = blockIdx.x, t = threadIdx.x;
  const int* deg = blockIdx.y ? degI : degO;
  int i = b*SCAN_B + t;
  int v = (i < N_NODES) ? deg[i] : 0;
  #pragma unroll
  for (int m = 1; m < 64; m <<= 1) v += __shfl_xor(v, m);
  __shared__ int ws[SCAN_B/64];
  if ((t & 63) == 0) ws[t >> 6] = v;
  __syncthreads();
  if (t == 0){
    int s = 0;
    for (int w = 0; w < SCAN_B/64; ++w) s += ws[w];
    bsum[blockIdx.y*SCAN_NB + b] = s;
  }
}
__global__ void k_scan2(int* bsum, int* offO, int* offI){
  if (threadIdx.x == 0){
    int run = 0;
    for (int i = 0; i < SCAN_NB; ++i){ int v = bsum[i]; bsum[i] = run; run += v; }
    offO[N_NODES] = run;
    run = 0;
    for (int i = 0; i < SCAN_NB; ++i){ int v = bsum[SCAN_NB+i]; bsum[SCAN_NB+i] = run; run += v; }
    offI[N_NODES] = run;
  }
}
__global__ __launch_bounds__(SCAN_B) void k_scan3(const int* __restrict__ degO,
                                                  const int* __restrict__ degI,
                                                  const int* __restrict__ bsum,
                                                  int* offO, int* offI){
  int b = blockIdx.x, t = threadIdx.x, lane = t & 63, w = t >> 6;
  const int* deg = blockIdx.y ? degI : degO;
  int* off = blockIdx.y ? offI : offO;
  int i = b*SCAN_B + t;
  int v = (i < N_NODES) ? deg[i] : 0;
  int x = v;
  #pragma unroll
  for (int m = 1; m < 64; m <<= 1){ int tt = __shfl_up(x, m); if (lane >= m) x += tt; }
  __shared__ int ws[SCAN_B/64];
  if (lane == 63) ws[w] = x;
  __syncthreads();
  int woff = 0;
  for (int k = 0; k < w; ++k) woff += ws[k];
  if (i < N_NODES) off[i] = bsum[blockIdx.y*SCAN_NB + b] + woff + x - v;
}

__global__ void k_scatter(const int* __restrict__ ei, const int* __restrict__ offO,
                          const int* __restrict__ offI, int* cursO, int* cursI,
                          int* csrO, int* csrI){
  int e = blockIdx.x*256 + threadIdx.x;
  if (e >= N_EDGES) return;
  int s = ei[e], t = ei[N_EDGES + e];
  int p = atomicAdd(&cursO[t], 1); csrO[offO[t] + p] = s;
  int q = atomicAdd(&cursI[s], 1); csrI[offI[s] + q] = t;
}

// ---------------- weight packing (f32 sources -> bf16 WT) ----------------
__global__ void k_pack_wt(const float* __restrict__ Wself, const float* __restrict__ Wctx,
                          const float* __restrict__ A1, u16* __restrict__ WT){
  int idx = blockIdx.x*256 + threadIdx.x;
  if (idx >= LL*NCOLS*DD) return;
  int k = idx & 127;
  int j = (idx >> 7) % NCOLS;
  int l = idx / (NCOLS*DD);
  const float* Ws = Wself + (size_t)l*DD*HH;
  const float* Wc = Wctx + (size_t)l*2*DD*HH;
  const float* A  = A1 + (size_t)l*HH*AHH;
  float v = 0.f;
  if (j < 128) v = Ws[k*HH + j];
  else if (j < 256) v = Wc[k*HH + (j-128)];
  else if (j < 384) v = Wc[(128+k)*HH + (j-256)] - Wc[k*HH + (j-256)];
  else if (j < 400){ int a = j-384; for (int h=0; h<HH; ++h) v += Ws[k*HH+h] * A[h*AHH+a]; }
  else if (j < 416){ int a = j-400; for (int h=0; h<HH; ++h) v += Wc[k*HH+h] * A[h*AHH+a]; }
  else { int a = j-416; for (int h=0; h<HH; ++h) v += (Wc[(128+k)*HH+h] - Wc[k*HH+h]) * A[h*AHH+a]; }
  WT[((size_t)l*NCOLS + j)*DD + k] = f2bf(v);
}

__global__ void k_pack_bias(const float* __restrict__ bs, const float* __restrict__ bc,
                            const float* __restrict__ A1, float* bsA, float* bcA){
  int i = threadIdx.x;
  if (i >= LL*2*AHH) return;
  int l = i >> 5, which = (i >> 4) & 1, a = i & 15;
  const float* b = which ? (bc + l*HH) : (bs + l*HH);
  const float* A = A1 + (size_t)l*HH*AHH;
  float v = 0.f;
  for (int h = 0; h < HH; ++h) v += b[h] * A[h*AHH + a];
  (which ? bcA : bsA)[l*AHH + a] = v;
}

// ---------------- fused GEMM with LDS-staged WT tiles ----------------
struct GemmOut { u16 *S, *P1, *Pd, *SA, *P1A, *PdA; };

__global__ __launch_bounds__(256) void k_gemm(const u16* __restrict__ X,
                                              const u16* __restrict__ WT, GemmOut o){
  __shared__ u16 lw[16*WTPAD];
  int tid = threadIdx.x;
  int wid = tid >> 6, lane = tid & 63;
  int m0 = (blockIdx.x*4 + wid)*16;
  bool mvalid = (m0 < N_NODES);
  int m0c = mvalid ? m0 : (N_NODES - 16);
  int l15 = lane & 15, quad = lane >> 4;
  int sr = tid >> 4, sp = tid & 15;   // staging role: row, 8-u16 part

  f32x4 acc[27];
  #pragma unroll
  for (int j = 0; j < 27; ++j) acc[j] = (f32x4){0.f,0.f,0.f,0.f};

  const u16* xr = X + (size_t)(m0c + l15)*DD + quad*8;
  short8 a[4];
  #pragma unroll
  for (int ks = 0; ks < 4; ++ks) a[ks] = *(const short8*)(xr + ks*32);

  short8 st = *(const short8*)(WT + (size_t)sr*DD + sp*8);   // prefetch tile 0
  for (int j = 0; j < 27; ++j){
    __syncthreads();   // prior iter's LDS reads done
    *(short8*)(&lw[sr*WTPAD + sp*8]) = st;
    __syncthreads();   // tile visible
    if (j+1 < 27) st = *(const short8*)(WT + ((size_t)(j+1)*16 + sr)*DD + sp*8);
    const u16* wb = &lw[l15*WTPAD + quad*8];
    #pragma unroll
    for (int ks = 0; ks < 4; ++ks){
      short8 b = *(const short8*)(wb + ks*32);
      acc[j] = __builtin_amdgcn_mfma_f32_16x16x32_bf16(a[ks], b, acc[j], 0, 0, 0);
    }
  }
  if (!mvalid) return;
  #pragma unroll
  for (int j = 0; j < 27; ++j){
    int col = j*16 + l15;
    #pragma unroll
    for (int r = 0; r < 4; ++r){
      int row = m0 + quad*4 + r;
      u16 hv = f2bf(acc[j][r]);
      if (col < 128)      o.S  [(size_t)row*128 + col]       = hv;
      else if (col < 256) o.P1 [(size_t)row*128 + col - 128] = hv;
      else if (col < 384) o.Pd [(size_t)row*128 + col - 256] = hv;
      else if (col < 400) o.SA [(size_t)row*16  + col - 384] = hv;
      else if (col < 416) o.P1A[(size_t)row*16  + col - 400] = hv;
      else                o.PdA[(size_t)row*16  + col - 416] = hv;
    }
  }
}

// ---------------- chunked gather, pollution-controlled ----------------
// blockIdx.y = feature chunk (32 feats = 3.2 MB L2 window). csr via nontemporal
// loads, Agg via nontemporal stores so streams don't evict the Pd window.
// Chunk 0 additionally accumulates the PdA attention gather (AggA).
__global__ __launch_bounds__(256) void k_gather(const u16* __restrict__ Pd,
    const u16* __restrict__ PdA,
    const int* __restrict__ offO, const int* __restrict__ offI,
    const int* __restrict__ csrO, const int* __restrict__ csrI,
    float* __restrict__ Agg /* [n][2][128] */, float* __restrict__ AggA /* [n][2][16] */){
  int n = blockIdx.x*4 + (threadIdx.x >> 6);
  int c = blockIdx.y;
  int lane = threadIdx.x & 63;
  int l16 = lane & 15, g = lane >> 4;
  const u16* PdC = Pd + c*32 + 2*l16;
  #pragma unroll
  for (int dir = 0; dir < 2; ++dir){
    const int* off = dir ? offI : offO;
    const int* csr = dir ? csrI : csrO;
    int beg = off[n], end = off[n+1];
    float a0 = 0.f, a1 = 0.f, b0 = 0.f, b1 = 0.f, pa = 0.f;
    int e = beg + g;
    if (c == 0){
      for (; e + 4 < end; e += 8){
        int nb0 = __builtin_nontemporal_load(csr + e);
        int nb1 = __builtin_nontemporal_load(csr + e + 4);
        u32 v0 = *(const u32*)(PdC + (size_t)nb0*128);
        u32 v1 = *(const u32*)(PdC + (size_t)nb1*128);
        pa += bf2f(PdA[(size_t)nb0*16 + l16]) + bf2f(PdA[(size_t)nb1*16 + l16]);
        a0 += bflo(v0); a1 += bfhi(v0);
        b0 += bflo(v1); b1 += bfhi(v1);
      }
      if (e < end){
        int nb = __builtin_nontemporal_load(csr + e);
        u32 v = *(const u32*)(PdC + (size_t)nb*128);
        pa += bf2f(PdA[(size_t)nb*16 + l16]);
        a0 += bflo(v); a1 += bfhi(v);
      }
    } else {
      for (; e + 4 < end; e += 8){
        int nb0 = __builtin_nontemporal_load(csr + e);
        int nb1 = __builtin_nontemporal_load(csr + e + 4);
        u32 v0 = *(const u32*)(PdC + (size_t)nb0*128);
        u32 v1 = *(const u32*)(PdC + (size_t)nb1*128);
        a0 += bflo(v0); a1 += bfhi(v0);
        b0 += bflo(v1); b1 += bfhi(v1);
      }
      if (e < end){
        u32 v = *(const u32*)(PdC + (size_t)__builtin_nontemporal_load(csr + e)*128);
        a0 += bflo(v); a1 += bfhi(v);
      }
    }
    a0 += b0; a1 += b1;
    a0 += __shfl_xor(a0, 16); a0 += __shfl_xor(a0, 32);
    a1 += __shfl_xor(a1, 16); a1 += __shfl_xor(a1, 32);
    if (c == 0){
      pa += __shfl_xor(pa, 16); pa += __shfl_xor(pa, 32);
    }
    if (g == 0){
      f32x2 r = (f32x2){a0, a1};
      __builtin_nontemporal_store(r, (f32x2*)(Agg + ((size_t)n*2 + dir)*128 + c*32 + 2*l16));
      if (c == 0) __builtin_nontemporal_store(pa, AggA + (size_t)n*32 + dir*16 + l16);
    }
  }
}

// ------- epilogue: attention + LN + residual + classifier-accumulate (no csr) -------
__global__ __launch_bounds__(256) void k_epi(int l,
  const u16* __restrict__ S, const u16* __restrict__ P1,
  const u16* __restrict__ SA, const u16* __restrict__ P1A,
  const float* __restrict__ Agg, const float* __restrict__ AggA,
  const int* __restrict__ degO, const int* __restrict__ degI,
  const float* __restrict__ b_self, const float* __restrict__ b_ctx,
  const float* __restrict__ bsA, const float* __restrict__ bcA,
  const float* __restrict__ att_b1, const float* __restrict__ att_w2,
  const float* __restrict__ gamma, const float* __restrict__ beta,
  const float* __restrict__ flog,
  float* __restrict__ xf, u16* __restrict__ xb16,
  const float* __restrict__ clsW, const float* __restrict__ clsB,
  float* __restrict__ out)
{
  int n = (blockIdx.x * 256 + threadIdx.x) >> 6;
  int lane = threadIdx.x & 63;
  int f0 = lane * 2;
  int a16 = lane & 15, g = lane >> 4;

  float2 ao = *(const float2*)(Agg + ((size_t)n*2 + 0)*128 + f0);
  float2 ai = *(const float2*)(Agg + ((size_t)n*2 + 1)*128 + f0);
  float aoa = AggA[(size_t)n*32 + a16];
  float aia = AggA[(size_t)n*32 + 16 + a16];
  float dO = (float)degO[n], dI = (float)degI[n];

  u32 sv = *(const u32*)(S  + (size_t)n*128 + f0);
  u32 pv = *(const u32*)(P1 + (size_t)n*128 + f0);
  float2 bsv = *(const float2*)(b_self + l*128 + f0);
  float2 bcv = *(const float2*)(b_ctx  + l*128 + f0);
  float p10 = bflo(pv), p11 = bfhi(pv);
  float mv00 = bflo(sv) + bsv.x;
  float mv01 = bfhi(sv) + bsv.y;
  float mv10 = dO*p10 + ao.x + bcv.x, mv11 = dO*p11 + ao.y + bcv.y;
  float mv20 = dI*p10 + ai.x + bcv.x, mv21 = dI*p11 + ai.y + bcv.y;

  // attention: lanes [v*16 + a], v<3 compute tanh(t + b1)*w2, reduce over a
  int a = a16, v = g;
  float u = 0.f;
  if (v < 3){
    float t;
    if (v == 0)      t = bf2f(SA[(size_t)n*16 + a]) + bsA[l*16 + a];
    else if (v == 1) t = dO*bf2f(P1A[(size_t)n*16 + a]) + aoa + bcA[l*16 + a];
    else             t = dI*bf2f(P1A[(size_t)n*16 + a]) + aia + bcA[l*16 + a];
    u = tanhf(t + att_b1[l*16 + a]) * att_w2[l*16 + a];
  }
  u += __shfl_xor(u, 1); u += __shfl_xor(u, 2);
  u += __shfl_xor(u, 4); u += __shfl_xor(u, 8);
  float s0 = __shfl(u, 0), s1 = __shfl(u, 16), s2 = __shfl(u, 32);
  float mx = fmaxf(s0, fmaxf(s1, s2));
  float e0 = __expf(s0-mx), e1 = __expf(s1-mx), e2 = __expf(s2-mx);
  float inv = 1.f / (e0 + e1 + e2);
  float w0 = e0*inv, w1 = e1*inv, w2v = e2*inv;
  float h0 = w0*mv00 + w1*mv10 + w2v*mv20;
  float h1 = w0*mv01 + w1*mv11 + w2v*mv21;

  // layer norm over 128
  float sum = h0 + h1, sq = h0*h0 + h1*h1;
  #pragma unroll
  for (int m = 1; m < 64; m <<= 1){ sum += __shfl_xor(sum, m); sq += __shfl_xor(sq, m); }
  float mu = sum * (1.f/128.f);
  float var = sq * (1.f/128.f) - mu*mu;
  float rs = rsqrtf(var + LN_EPS);
  float2 gv = *(const float2*)(gamma + l*128 + f0);
  float2 bv = *(const float2*)(beta  + l*128 + f0);
  float y0 = fmaxf((h0 - mu)*rs*gv.x + bv.x, 0.f);
  float y1 = fmaxf((h1 - mu)*rs*gv.y + bv.y, 0.f);
  float xn0 = y0, xn1 = y1;
  if (l > 0){
    float2 xv = *(const float2*)(xf + (size_t)n*128 + f0);
    xn0 += xv.x; xn1 += xv.y;
  }
  *(float2*)(xf + (size_t)n*128 + f0) = make_float2(xn0, xn1);
  *(u32*)(xb16 + (size_t)n*128 + f0) = (u32)f2bf(xn0) | ((u32)f2bf(xn1) << 16);

  float g0 = flog[0], g1 = flog[1], g2 = flog[2], g3 = flog[3];
  float gm = fmaxf(fmaxf(g0,g1), fmaxf(g2,g3));
  float q0 = __expf(g0-gm), q1 = __expf(g1-gm), q2 = __expf(g2-gm), q3 = __expf(g3-gm);
  float fwl = (l==0?q0 : l==1?q1 : l==2?q2 : q3) / (q0+q1+q2+q3);

  float4 w = *(const float4*)(clsW + lane*4);
  float o0 = xn0*w.x + xn1*w.z;
  float o1 = xn0*w.y + xn1*w.w;
  #pragma unroll
  for (int m = 1; m < 64; m <<= 1){ o0 += __shfl_xor(o0, m); o1 += __shfl_xor(o1, m); }
  if (lane == 0){
    float2* op = (float2*)(out + (size_t)n*2);
    float2 prev = (l > 0) ? *op : make_float2(0.f, 0.f);
    float r0 = prev.x + fwl*o0, r1 = prev.y + fwl*o1;
    if (l == LL-1){ r0 += clsB[0]; r1 += clsB[1]; }
    *op = make_float2(r0, r1);
  }
}

// ------- fallback fused kernel (R5 path) used when workspace can't hold Agg -------
__global__ __launch_bounds__(256) void k_aggepi(int l,
  const u16* __restrict__ S, const u16* __restrict__ P1,
  const u16* __restrict__ Pd, const u16* __restrict__ SA,
  const u16* __restrict__ P1A, const u16* __restrict__ PdA,
  const int* __restrict__ offO, const int* __restrict__ offI,
  const int* __restrict__ csrO, const int* __restrict__ csrI,
  const float* __restrict__ b_self, const float* __restrict__ b_ctx,
  const float* __restrict__ bsA, const float* __restrict__ bcA,
  const float* __restrict__ att_b1, const float* __restrict__ att_w2,
  const float* __restrict__ gamma, const float* __restrict__ beta,
  const float* __restrict__ flog,
  float* __restrict__ xf, u16* __restrict__ xb16,
  const float* __restrict__ clsW, const float* __restrict__ clsB,
  float* __restrict__ out)
{
  int n = (blockIdx.x * 256 + threadIdx.x) >> 6;
  int lane = threadIdx.x & 63;
  int f0 = lane * 2;
  const u16* PdF = Pd + f0;
  int begO = offO[n], endO = offO[n+1];
  int begI = offI[n], endI = offI[n+1];
  float o00=0.f,o01=0.f,o10=0.f,o11=0.f;
  float i00=0.f,i01=0.f,i10=0.f,i11=0.f;
  int eO = begO, eI = begI;
  for (; eO + 2 <= endO && eI + 2 <= endI; eO += 2, eI += 2){
    u32 a0 = *(const u32*)(PdF + (size_t)csrO[eO]*128);
    u32 a1 = *(const u32*)(PdF + (size_t)csrO[eO+1]*128);
    u32 b0 = *(const u32*)(PdF + (size_t)csrI[eI]*128);
    u32 b1 = *(const u32*)(PdF + (size_t)csrI[eI+1]*128);
    o00 += bflo(a0); o01 += bfhi(a0); o10 += bflo(a1); o11 += bfhi(a1);
    i00 += bflo(b0); i01 += bfhi(b0); i10 += bflo(b1); i11 += bfhi(b1);
  }
  for (; eO < endO; ++eO){ u32 v = *(const u32*)(PdF + (size_t)csrO[eO]*128); o00 += bflo(v); o01 += bfhi(v); }
  for (; eI < endI; ++eI){ u32 v = *(const u32*)(PdF + (size_t)csrI[eI]*128); i00 += bflo(v); i01 += bfhi(v); }
  float ao0 = o00+o10, ao1 = o01+o11, ai0 = i00+i10, ai1 = i01+i11;
  int a16 = lane & 15, g = lane >> 4;
  float aoa = 0.f, aia = 0.f;
  for (int e2 = begO + g; e2 < endO; e2 += 4) aoa += bf2f(PdA[(size_t)csrO[e2]*16 + a16]);
  for (int e2 = begI + g; e2 < endI; e2 += 4) aia += bf2f(PdA[(size_t)csrI[e2]*16 + a16]);
  aoa += __shfl_xor(aoa, 16); aoa += __shfl_xor(aoa, 32);
  aia += __shfl_xor(aia, 16); aia += __shfl_xor(aia, 32);
  float dO = (float)(endO - begO), dI = (float)(endI - begI);
  u32 sv = *(const u32*)(S  + (size_t)n*128 + f0);
  u32 pv = *(const u32*)(P1 + (size_t)n*128 + f0);
  float2 bsv = *(const float2*)(b_self + l*128 + f0);
  float2 bcv = *(const float2*)(b_ctx  + l*128 + f0);
  float p10 = bflo(pv), p11 = bfhi(pv);
  float mv00 = bflo(sv) + bsv.x;
  float mv01 = bfhi(sv) + bsv.y;
  float mv10 = dO*p10 + ao0 + bcv.x, mv11 = dO*p11 + ao1 + bcv.y;
  float mv20 = dI*p10 + ai0 + bcv.x, mv21 = dI*p11 + ai1 + bcv.y;
  int a = a16, v = g;
  float u = 0.f;
  if (v < 3){
    float t;
    if (v == 0)      t = bf2f(SA[(size_t)n*16 + a]) + bsA[l*16 + a];
    else if (v == 1) t = dO*bf2f(P1A[(size_t)n*16 + a]) + aoa + bcA[l*16 + a];
    else             t = dI*bf2f(P1A[(size_t)n*16 + a]) + aia + bcA[l*16 + a];
    u = tanhf(t + att_b1[l*16 + a]) * att_w2[l*16 + a];
  }
  u += __shfl_xor(u, 1); u += __shfl_xor(u, 2);
  u += __shfl_xor(u, 4); u += __shfl_xor(u, 8);
  float s0 = __shfl(u, 0), s1 = __shfl(u, 16), s2 = __shfl(u, 32);
  float mx = fmaxf(s0, fmaxf(s1, s2));
  float e0 = __expf(s0-mx), e1 = __expf(s1-mx), e2 = __expf(s2-mx);
  float inv = 1.f / (e0 + e1 + e2);
  float w0 = e0*inv, w1 = e1*inv, w2v = e2*inv;
  float h0 = w0*mv00 + w1*mv10 + w2v*mv20;
  float h1 = w0*mv01 + w1*mv11 + w2v*mv21;
  float sum = h0 + h1, sq = h0*h0 + h1*h1;
  #pragma unroll
  for (int m = 1; m < 64; m <<= 1){ sum += __shfl_xor(sum, m); sq += __shfl_xor(sq, m); }
  float mu = sum * (1.f/128.f);
  float var = sq * (1.f/128.f) - mu*mu;
  float rs = rsqrtf(var + LN_EPS);
  float2 gv = *(const float2*)(gamma + l*128 + f0);
  float2 bv = *(const float2*)(beta  + l*128 + f0);
  float y0 = fmaxf((h0 - mu)*rs*gv.x + bv.x, 0.f);
  float y1 = fmaxf((h1 - mu)*rs*gv.y + bv.y, 0.f);
  float xn0 = y0, xn1 = y1;
  if (l > 0){
    float2 xv = *(const float2*)(xf + (size_t)n*128 + f0);
    xn0 += xv.x; xn1 += xv.y;
  }
  *(float2*)(xf + (size_t)n*128 + f0) = make_float2(xn0, xn1);
  *(u32*)(xb16 + (size_t)n*128 + f0) = (u32)f2bf(xn0) | ((u32)f2bf(xn1) << 16);
  float g0 = flog[0], g1 = flog[1], g2 = flog[2], g3 = flog[3];
  float gm = fmaxf(fmaxf(g0,g1), fmaxf(g2,g3));
  float q0 = __expf(g0-gm), q1 = __expf(g1-gm), q2 = __expf(g2-gm), q3 = __expf(g3-gm);
  float fwl = (l==0?q0 : l==1?q1 : l==2?q2 : q3) / (q0+q1+q2+q3);
  float4 w = *(const float4*)(clsW + lane*4);
  float o0 = xn0*w.x + xn1*w.z;
  float o1 = xn0*w.y + xn1*w.w;
  #pragma unroll
  for (int m = 1; m < 64; m <<= 1){ o0 += __shfl_xor(o0, m); o1 += __shfl_xor(o1, m); }
  if (lane == 0){
    float2* op = (float2*)(out + (size_t)n*2);
    float2 prev = (l > 0) ? *op : make_float2(0.f, 0.f);
    float r0 = prev.x + fwl*o0, r1 = prev.y + fwl*o1;
    if (l == LL-1){ r0 += clsB[0]; r1 += clsB[1]; }
    *op = make_float2(r0, r1);
  }
}

extern "C" void kernel_launch(void* const* d_in, const int* in_sizes, int n_in,
                              void* d_out, int out_size, void* d_ws, size_t ws_size,
                              hipStream_t stream){
  const float* X0    = (const float*)d_in[0];
  const int*   EI    = (const int*)d_in[1];
  const float* Wself = (const float*)d_in[2];
  const float* bs    = (const float*)d_in[3];
  const float* Wctx  = (const float*)d_in[4];
  const float* bc    = (const float*)d_in[5];
  const float* A1    = (const float*)d_in[6];
  const float* ab1   = (const float*)d_in[7];
  const float* aw2   = (const float*)d_in[8];
  const float* gam   = (const float*)d_in[9];
  const float* bet   = (const float*)d_in[10];
  const float* flog  = (const float*)d_in[11];
  const float* clsW  = (const float*)d_in[12];
  const float* clsB  = (const float*)d_in[13];
  float* out = (float*)d_out;

  char* wsp = (char*)d_ws;
  size_t o = 0;
  auto alloc = [&](size_t b)->char*{ char* p = wsp + o; o = (o + b + 255) & ~(size_t)255; return p; };
  u16*  xb16  = (u16*) alloc((size_t)N_NODES*128*2);
  float* xf   = (float*)alloc((size_t)N_NODES*128*4);
  u16*  S     = (u16*) alloc((size_t)N_NODES*128*2);
  u16*  P1    = (u16*) alloc((size_t)N_NODES*128*2);
  u16*  Pd    = (u16*) alloc((size_t)N_NODES*128*2);
  u16*  SAb   = (u16*) alloc((size_t)N_NODES*16*2);
  u16*  P1A   = (u16*) alloc((size_t)N_NODES*16*2);
  u16*  PdA   = (u16*) alloc((size_t)N_NODES*16*2);
  u16*  WT    = (u16*) alloc((size_t)LL*NCOLS*128*2);
  float* bsA  = (float*)alloc(LL*16*4);
  float* bcA  = (float*)alloc(LL*16*4);
  int* bsum   = (int*) alloc((size_t)2*SCAN_NB*4);
  int* degO   = (int*) alloc((size_t)N_NODES*4);
  int* degI   = (int*) alloc((size_t)N_NODES*4);
  int* cursO  = (int*) alloc((size_t)N_NODES*4);
  int* cursI  = (int*) alloc((size_t)N_NODES*4);
  int* offO   = (int*) alloc((size_t)(N_NODES+1)*4);
  int* offI   = (int*) alloc((size_t)(N_NODES+1)*4);
  int* csrO   = (int*) alloc((size_t)N_EDGES*4);
  int* csrI   = (int*) alloc((size_t)N_EDGES*4);
  size_t base_need = o;
  float* Agg  = (float*)alloc((size_t)N_NODES*2*128*4);   // split-path only
  float* AggA = (float*)alloc((size_t)N_NODES*2*16*4);    // split-path only
  int split = (ws_size >= o) ? 1 : 0;

  if (ws_size < base_need){
    k_fail<<<(N_NODES*2+255)/256, 256, 0, stream>>>(out);
    return;
  }

  (void)hipMemsetAsync(degO, 0, (size_t)((char*)offO - (char*)degO), stream);

  k_cvt<<<(N_NODES*DD+255)/256, 256, 0, stream>>>(X0, xb16);
  k_hist<<<(N_EDGES+255)/256, 256, 0, stream>>>(EI, degO, degI);
  k_scan1<<<dim3(SCAN_NB,2), SCAN_B, 0, stream>>>(degO, degI, bsum);
  k_scan2<<<1, 64, 0, stream>>>(bsum, offO, offI);
  k_scan3<<<dim3(SCAN_NB,2), SCAN_B, 0, stream>>>(degO, degI, bsum, offO, offI);
  k_scatter<<<(N_EDGES+255)/256, 256, 0, stream>>>(EI, offO, offI, cursO, cursI, csrO, csrI);
  k_pack_wt<<<(LL*NCOLS*128+255)/256, 256, 0, stream>>>(Wself, Wctx, A1, WT);
  k_pack_bias<<<1, 128, 0, stream>>>(bs, bc, A1, bsA, bcA);

  GemmOut go{S, P1, Pd, SAb, P1A, PdA};
  const int gemm_blocks = ((N_NODES/16) + 3) / 4;
  for (int l = 0; l < LL; ++l){
    k_gemm<<<gemm_blocks, 256, 0, stream>>>(xb16, WT + (size_t)l*NCOLS*128, go);
    if (split){
      k_gather<<<dim3(N_NODES/4, 4), 256, 0, stream>>>(Pd, PdA, offO, offI, csrO, csrI,
                                                       Agg, AggA);
      k_epi<<<N_NODES/4, 256, 0, stream>>>(l, S, P1, SAb, P1A, Agg, AggA,
                                           degO, degI,
                                           bs, bc, bsA, bcA, ab1, aw2,
                                           gam, bet, flog, xf, xb16,
                                           clsW, clsB, out);
    } else {
      k_aggepi<<<N_NODES/4, 256, 0, stream>>>(l, S, P1, Pd, SAb, P1A, PdA,
                                              offO, offI, csrO, csrI,
                                              bs, bc, bsA, bcA, ab1, aw2,
                                              gam, bet, flog, xf, xb16,
                                              clsW, clsB, out);
    }
  }
}

// Round 9
// 863.171 us; speedup vs baseline: 1.5225x; 1.4229x over previous
//
#include <hip/hip_runtime.h>

#define N_NODES 50000
#define N_EDGES 800000
#define DD 128
#define HH 128
#define LL 4
#define AHH 16
#define LN_EPS 1e-5f
#define NCOLS 432   // 128 S | 128 P1 | 128 Pd | 16 SA | 16 P1A | 16 PdA
#define SCAN_B 512
#define SCAN_NB ((N_NODES + SCAN_B - 1) / SCAN_B)
#define WTPAD 136

typedef unsigned short u16;
typedef unsigned int u32;
typedef __attribute__((ext_vector_type(8))) short short8;
typedef __attribute__((ext_vector_type(4))) float f32x4;

__device__ __forceinline__ float bf2f(u16 h){
  u32 u = ((u32)h) << 16;
  return __builtin_bit_cast(float, u);
}
__device__ __forceinline__ float bflo(u32 v){ return __builtin_bit_cast(float, v << 16); }
__device__ __forceinline__ float bfhi(u32 v){ return __builtin_bit_cast(float, v & 0xffff0000u); }
__device__ __forceinline__ u16 f2bf(float x){
  u32 u = __builtin_bit_cast(u32, x);
  u += 0x7fffu + ((u >> 16) & 1u);
  return (u16)(u >> 16);
}

// ---------------- sentinel (workspace too small) ----------------
__global__ void k_fail(float* out){
  int i = blockIdx.x*256 + threadIdx.x;
  if (i < N_NODES*2) out[i] = 1.0e6f;
}

// ---------------- f32 -> bf16 conversion of node features ----------------
__global__ void k_cvt(const float* __restrict__ X, u16* __restrict__ Xb){
  int i = blockIdx.x*256 + threadIdx.x;
  if (i < N_NODES*DD) Xb[i] = f2bf(X[i]);
}

// ---------------- CSR build ----------------
__global__ void k_hist(const int* __restrict__ ei, int* degO, int* degI){
  int e = blockIdx.x*256 + threadIdx.x;
  if (e >= N_EDGES) return;
  atomicAdd(&degO[ei[N_EDGES + e]], 1);  // tgt histogram (outgoing view)
  atomicAdd(&degI[ei[e]], 1);            // src histogram (incoming view)
}

// 3-phase parallel exclusive scan
__global__ __launch_bounds__(SCAN_B) void k_scan1(const int* __restrict__ degO,
                                                  const int* __restrict__ degI, int* bsum){
  int b = blockIdx.x, t = threadIdx.x;
  const int* deg = blockIdx.y ? degI : degO;
  int i = b*SCAN_B + t;
  int v = (i < N_NODES) ? deg[i] : 0;
  #pragma unroll
  for (int m = 1; m < 64; m <<= 1) v += __shfl_xor(v, m);
  __shared__ int ws[SCAN_B/64];
  if ((t & 63) == 0) ws[t >> 6] = v;
  __syncthreads();
  if (t == 0){
    int s = 0;
    for (int w = 0; w < SCAN_B/64; ++w) s += ws[w];
    bsum[blockIdx.y*SCAN_NB + b] = s;
  }
}
__global__ void k_scan2(int* bsum, int* offO, int* offI){
  if (threadIdx.x == 0){
    int run = 0;
    for (int i = 0; i < SCAN_NB; ++i){ int v = bsum[i]; bsum[i] = run; run += v; }
    offO[N_NODES] = run;
    run = 0;
    for (int i = 0; i < SCAN_NB; ++i){ int v = bsum[SCAN_NB+i]; bsum[SCAN_NB+i] = run; run += v; }
    offI[N_NODES] = run;
  }
}
__global__ __launch_bounds__(SCAN_B) void k_scan3(const int* __restrict__ degO,
                                                  const int* __restrict__ degI,
                                                  const int* __restrict__ bsum,
                                                  int* offO, int* offI){
  int b = blockIdx.x, t = threadIdx.x, lane = t & 63, w = t >> 6;
  const int* deg = blockIdx.y ? degI : degO;
  int* off = blockIdx.y ? offI : offO;
  int i = b*SCAN_B + t;
  int v = (i < N_NODES) ? deg[i] : 0;
  int x = v;
  #pragma unroll
  for (int m = 1; m < 64; m <<= 1){ int tt = __shfl_up(x, m); if (lane >= m) x += tt; }
  __shared__ int ws[SCAN_B/64];
  if (lane == 63) ws[w] = x;
  __syncthreads();
  int woff = 0;
  for (int k = 0; k < w; ++k) woff += ws[k];
  if (i < N_NODES) off[i] = bsum[blockIdx.y*SCAN_NB + b] + woff + x - v;
}

__global__ void k_scatter(const int* __restrict__ ei, const int* __restrict__ offO,
                          const int* __restrict__ offI, int* cursO, int* cursI,
                          int* csrO, int* csrI){
  int e = blockIdx.x*256 + threadIdx.x;
  if (e >= N_EDGES) return;
  int s = ei[e], t = ei[N_EDGES + e];
  int p = atomicAdd(&cursO[t], 1); csrO[offO[t] + p] = s;
  int q = atomicAdd(&cursI[s], 1); csrI[offI[s] + q] = t;
}

// ---------------- weight packing (f32 sources -> bf16 WT) ----------------
__global__ void k_pack_wt(const float* __restrict__ Wself, const float* __restrict__ Wctx,
                          const float* __restrict__ A1, u16* __restrict__ WT){
  int idx = blockIdx.x*256 + threadIdx.x;
  if (idx >= LL*NCOLS*DD) return;
  int k = idx & 127;
  int j = (idx >> 7) % NCOLS;
  int l = idx / (NCOLS*DD);
  const float* Ws = Wself + (size_t)l*DD*HH;
  const float* Wc = Wctx + (size_t)l*2*DD*HH;
  const float* A  = A1 + (size_t)l*HH*AHH;
  float v = 0.f;
  if (j < 128) v = Ws[k*HH + j];
  else if (j < 256) v = Wc[k*HH + (j-128)];
  else if (j < 384) v = Wc[(128+k)*HH + (j-256)] - Wc[k*HH + (j-256)];
  else if (j < 400){ int a = j-384; for (int h=0; h<HH; ++h) v += Ws[k*HH+h] * A[h*AHH+a]; }
  else if (j < 416){ int a = j-400; for (int h=0; h<HH; ++h) v += Wc[k*HH+h] * A[h*AHH+a]; }
  else { int a = j-416; for (int h=0; h<HH; ++h) v += (Wc[(128+k)*HH+h] - Wc[k*HH+h]) * A[h*AHH+a]; }
  WT[((size_t)l*NCOLS + j)*DD + k] = f2bf(v);
}

__global__ void k_pack_bias(const float* __restrict__ bs, const float* __restrict__ bc,
                            const float* __restrict__ A1, float* bsA, float* bcA){
  int i = threadIdx.x;
  if (i >= LL*2*AHH) return;
  int l = i >> 5, which = (i >> 4) & 1, a = i & 15;
  const float* b = which ? (bc + l*HH) : (bs + l*HH);
  const float* A = A1 + (size_t)l*HH*AHH;
  float v = 0.f;
  for (int h = 0; h < HH; ++h) v += b[h] * A[h*AHH + a];
  (which ? bcA : bsA)[l*AHH + a] = v;
}

// ---------------- fused GEMM with LDS-staged WT tiles ----------------
struct GemmOut { u16 *S, *P1, *Pd, *SA, *P1A, *PdA; };

__global__ __launch_bounds__(256) void k_gemm(const u16* __restrict__ X,
                                              const u16* __restrict__ WT, GemmOut o){
  __shared__ u16 lw[16*WTPAD];
  int tid = threadIdx.x;
  int wid = tid >> 6, lane = tid & 63;
  int m0 = (blockIdx.x*4 + wid)*16;
  bool mvalid = (m0 < N_NODES);
  int m0c = mvalid ? m0 : (N_NODES - 16);
  int l15 = lane & 15, quad = lane >> 4;
  int sr = tid >> 4, sp = tid & 15;   // staging role: row, 8-u16 part

  f32x4 acc[27];
  #pragma unroll
  for (int j = 0; j < 27; ++j) acc[j] = (f32x4){0.f,0.f,0.f,0.f};

  const u16* xr = X + (size_t)(m0c + l15)*DD + quad*8;
  short8 a[4];
  #pragma unroll
  for (int ks = 0; ks < 4; ++ks) a[ks] = *(const short8*)(xr + ks*32);

  short8 st = *(const short8*)(WT + (size_t)sr*DD + sp*8);   // prefetch tile 0
  for (int j = 0; j < 27; ++j){
    __syncthreads();
    *(short8*)(&lw[sr*WTPAD + sp*8]) = st;
    __syncthreads();
    if (j+1 < 27) st = *(const short8*)(WT + ((size_t)(j+1)*16 + sr)*DD + sp*8);
    const u16* wb = &lw[l15*WTPAD + quad*8];
    #pragma unroll
    for (int ks = 0; ks < 4; ++ks){
      short8 b = *(const short8*)(wb + ks*32);
      acc[j] = __builtin_amdgcn_mfma_f32_16x16x32_bf16(a[ks], b, acc[j], 0, 0, 0);
    }
  }
  if (!mvalid) return;
  #pragma unroll
  for (int j = 0; j < 27; ++j){
    int col = j*16 + l15;
    #pragma unroll
    for (int r = 0; r < 4; ++r){
      int row = m0 + quad*4 + r;
      u16 hv = f2bf(acc[j][r]);
      if (col < 128)      o.S  [(size_t)row*128 + col]       = hv;
      else if (col < 256) o.P1 [(size_t)row*128 + col - 128] = hv;
      else if (col < 384) o.Pd [(size_t)row*128 + col - 256] = hv;
      else if (col < 400) o.SA [(size_t)row*16  + col - 384] = hv;
      else if (col < 416) o.P1A[(size_t)row*16  + col - 400] = hv;
      else                o.PdA[(size_t)row*16  + col - 416] = hv;
    }
  }
}

// ------- fused CSR gather + attention + LN + residual + classifier (R5-proven) -------
__global__ __launch_bounds__(256) void k_aggepi(int l,
  const u16* __restrict__ S, const u16* __restrict__ P1,
  const u16* __restrict__ Pd, const u16* __restrict__ SA,
  const u16* __restrict__ P1A, const u16* __restrict__ PdA,
  const int* __restrict__ offO, const int* __restrict__ offI,
  const int* __restrict__ csrO, const int* __restrict__ csrI,
  const float* __restrict__ b_self, const float* __restrict__ b_ctx,
  const float* __restrict__ bsA, const float* __restrict__ bcA,
  const float* __restrict__ att_b1, const float* __restrict__ att_w2,
  const float* __restrict__ gamma, const float* __restrict__ beta,
  const float* __restrict__ flog,
  u16* __restrict__ xb16,
  const float* __restrict__ clsW, const float* __restrict__ clsB,
  float* __restrict__ out)
{
  int n = (blockIdx.x * 256 + threadIdx.x) >> 6;
  int lane = threadIdx.x & 63;
  int f0 = lane * 2;
  const u16* PdF = Pd + f0;           // per-lane column base into Pd rows

  int begO = offO[n], endO = offO[n+1];
  int begI = offI[n], endI = offI[n+1];

  float o00=0.f,o01=0.f,o10=0.f,o11=0.f,o20=0.f,o21=0.f,o30=0.f,o31=0.f;
  float i00=0.f,i01=0.f,i10=0.f,i11=0.f,i20=0.f,i21=0.f,i30=0.f,i31=0.f;

  int eO = begO, eI = begI;
  // scalar alignment heads: make eO/eI multiples of 4 (csr bases are 256B-aligned)
  for (; eO < endO && (eO & 3); ++eO){
    u32 v = *(const u32*)(PdF + (size_t)csrO[eO]*128);
    o00 += bflo(v); o01 += bfhi(v);
  }
  for (; eI < endI && (eI & 3); ++eI){
    u32 v = *(const u32*)(PdF + (size_t)csrI[eI]*128);
    i00 += bflo(v); i01 += bfhi(v);
  }
  // fused main loop: 4 outgoing + 4 incoming gathers in flight, int4 index loads
  for (; eO + 4 <= endO && eI + 4 <= endI; eO += 4, eI += 4){
    int4 nO = *(const int4*)(csrO + eO);
    int4 nI = *(const int4*)(csrI + eI);
    u32 a0 = *(const u32*)(PdF + (size_t)nO.x*128);
    u32 a1 = *(const u32*)(PdF + (size_t)nO.y*128);
    u32 a2 = *(const u32*)(PdF + (size_t)nO.z*128);
    u32 a3 = *(const u32*)(PdF + (size_t)nO.w*128);
    u32 b0 = *(const u32*)(PdF + (size_t)nI.x*128);
    u32 b1 = *(const u32*)(PdF + (size_t)nI.y*128);
    u32 b2 = *(const u32*)(PdF + (size_t)nI.z*128);
    u32 b3 = *(const u32*)(PdF + (size_t)nI.w*128);
    o00 += bflo(a0); o01 += bfhi(a0);
    o10 += bflo(a1); o11 += bfhi(a1);
    o20 += bflo(a2); o21 += bfhi(a2);
    o30 += bflo(a3); o31 += bfhi(a3);
    i00 += bflo(b0); i01 += bfhi(b0);
    i10 += bflo(b1); i11 += bfhi(b1);
    i20 += bflo(b2); i21 += bfhi(b2);
    i30 += bflo(b3); i31 += bfhi(b3);
  }
  // drain outgoing
  for (; eO + 4 <= endO; eO += 4){
    int4 nO = *(const int4*)(csrO + eO);
    u32 a0 = *(const u32*)(PdF + (size_t)nO.x*128);
    u32 a1 = *(const u32*)(PdF + (size_t)nO.y*128);
    u32 a2 = *(const u32*)(PdF + (size_t)nO.z*128);
    u32 a3 = *(const u32*)(PdF + (size_t)nO.w*128);
    o00 += bflo(a0); o01 += bfhi(a0);
    o10 += bflo(a1); o11 += bfhi(a1);
    o20 += bflo(a2); o21 += bfhi(a2);
    o30 += bflo(a3); o31 += bfhi(a3);
  }
  for (; eO < endO; ++eO){
    u32 v = *(const u32*)(PdF + (size_t)csrO[eO]*128);
    o00 += bflo(v); o01 += bfhi(v);
  }
  // drain incoming
  for (; eI + 4 <= endI; eI += 4){
    int4 nI = *(const int4*)(csrI + eI);
    u32 b0 = *(const u32*)(PdF + (size_t)nI.x*128);
    u32 b1 = *(const u32*)(PdF + (size_t)nI.y*128);
    u32 b2 = *(const u32*)(PdF + (size_t)nI.z*128);
    u32 b3 = *(const u32*)(PdF + (size_t)nI.w*128);
    i00 += bflo(b0); i01 += bfhi(b0);
    i10 += bflo(b1); i11 += bfhi(b1);
    i20 += bflo(b2); i21 += bfhi(b2);
    i30 += bflo(b3); i31 += bfhi(b3);
  }
  for (; eI < endI; ++eI){
    u32 v = *(const u32*)(PdF + (size_t)csrI[eI]*128);
    i00 += bflo(v); i01 += bfhi(v);
  }
  float ao0 = (o00+o10)+(o20+o30), ao1 = (o01+o11)+(o21+o31);
  float ai0 = (i00+i10)+(i20+i30), ai1 = (i01+i11)+(i21+i31);

  // --- PdA gathers: 4 edges per iteration via the four 16-lane groups ---
  int a16 = lane & 15, g = lane >> 4;
  float aoa = 0.f, aia = 0.f;
  for (int e2 = begO + g; e2 < endO; e2 += 4)
    aoa += bf2f(PdA[(size_t)csrO[e2]*16 + a16]);
  for (int e2 = begI + g; e2 < endI; e2 += 4)
    aia += bf2f(PdA[(size_t)csrI[e2]*16 + a16]);
  aoa += __shfl_xor(aoa, 16); aoa += __shfl_xor(aoa, 32);
  aia += __shfl_xor(aia, 16); aia += __shfl_xor(aia, 32);

  float dO = (float)(endO - begO), dI = (float)(endI - begI);

  // --- three views, 2 features per lane ---
  u32 sv = *(const u32*)(S  + (size_t)n*128 + f0);
  u32 pv = *(const u32*)(P1 + (size_t)n*128 + f0);
  float2 bsv = *(const float2*)(b_self + l*128 + f0);
  float2 bcv = *(const float2*)(b_ctx  + l*128 + f0);
  float p10 = bflo(pv), p11 = bfhi(pv);
  float mv00 = bflo(sv) + bsv.x;
  float mv01 = bfhi(sv) + bsv.y;
  float mv10 = dO*p10 + ao0 + bcv.x, mv11 = dO*p11 + ao1 + bcv.y;
  float mv20 = dI*p10 + ai0 + bcv.x, mv21 = dI*p11 + ai1 + bcv.y;

  // --- attention: lanes [v*16 + a], v<3 compute tanh(t + b1)*w2, reduce over a ---
  int a = a16, v = g;
  float u = 0.f;
  if (v < 3){
    float t;
    if (v == 0)      t = bf2f(SA[(size_t)n*16 + a]) + bsA[l*16 + a];
    else if (v == 1) t = dO*bf2f(P1A[(size_t)n*16 + a]) + aoa + bcA[l*16 + a];
    else             t = dI*bf2f(P1A[(size_t)n*16 + a]) + aia + bcA[l*16 + a];
    u = tanhf(t + att_b1[l*16 + a]) * att_w2[l*16 + a];
  }
  u += __shfl_xor(u, 1); u += __shfl_xor(u, 2);
  u += __shfl_xor(u, 4); u += __shfl_xor(u, 8);
  float s0 = __shfl(u, 0), s1 = __shfl(u, 16), s2 = __shfl(u, 32);
  float mx = fmaxf(s0, fmaxf(s1, s2));
  float e0 = __expf(s0-mx), e1 = __expf(s1-mx), e2 = __expf(s2-mx);
  float inv = 1.f / (e0 + e1 + e2);
  float w0 = e0*inv, w1 = e1*inv, w2v = e2*inv;
  float h0 = w0*mv00 + w1*mv10 + w2v*mv20;
  float h1 = w0*mv01 + w1*mv11 + w2v*mv21;

  // --- layer norm over 128 ---
  float sum = h0 + h1, sq = h0*h0 + h1*h1;
  #pragma unroll
  for (int m = 1; m < 64; m <<= 1){ sum += __shfl_xor(sum, m); sq += __shfl_xor(sq, m); }
  float mu = sum * (1.f/128.f);
  float var = sq * (1.f/128.f) - mu*mu;
  float rs = rsqrtf(var + LN_EPS);
  float2 gv = *(const float2*)(gamma + l*128 + f0);
  float2 bv = *(const float2*)(beta  + l*128 + f0);
  float y0 = fmaxf((h0 - mu)*rs*gv.x + bv.x, 0.f);
  float y1 = fmaxf((h1 - mu)*rs*gv.y + bv.y, 0.f);
  float xn0 = y0, xn1 = y1;
  if (l > 0){
    u32 xv = *(const u32*)(xb16 + (size_t)n*128 + f0);
    xn0 += bflo(xv); xn1 += bfhi(xv);
  }
  // bf16 residual stream (also next layer's GEMM input)
  *(u32*)(xb16 + (size_t)n*128 + f0) = (u32)f2bf(xn0) | ((u32)f2bf(xn1) << 16);

  // fusion weight (softmax over 4 logits)
  float g0 = flog[0], g1 = flog[1], g2 = flog[2], g3 = flog[3];
  float gm = fmaxf(fmaxf(g0,g1), fmaxf(g2,g3));
  float q0 = __expf(g0-gm), q1 = __expf(g1-gm), q2 = __expf(g2-gm), q3 = __expf(g3-gm);
  float fwl = (l==0?q0 : l==1?q1 : l==2?q2 : q3) / (q0+q1+q2+q3);

  // classifier accumulate: out[n,:] += fwl * (x_l[n] @ clsW); bias at last layer
  float4 w = *(const float4*)(clsW + lane*4);   // rows 2*lane, 2*lane+1 of [128,2]
  float o0 = xn0*w.x + xn1*w.z;
  float o1 = xn0*w.y + xn1*w.w;
  #pragma unroll
  for (int m = 1; m < 64; m <<= 1){ o0 += __shfl_xor(o0, m); o1 += __shfl_xor(o1, m); }
  if (lane == 0){
    float2* op = (float2*)(out + (size_t)n*2);
    float2 prev = (l > 0) ? *op : make_float2(0.f, 0.f);
    float r0 = prev.x + fwl*o0, r1 = prev.y + fwl*o1;
    if (l == LL-1){ r0 += clsB[0]; r1 += clsB[1]; }
    *op = make_float2(r0, r1);
  }
}

extern "C" void kernel_launch(void* const* d_in, const int* in_sizes, int n_in,
                              void* d_out, int out_size, void* d_ws, size_t ws_size,
                              hipStream_t stream){
  const float* X0    = (const float*)d_in[0];
  const int*   EI    = (const int*)d_in[1];
  const float* Wself = (const float*)d_in[2];
  const float* bs    = (const float*)d_in[3];
  const float* Wctx  = (const float*)d_in[4];
  const float* bc    = (const float*)d_in[5];
  const float* A1    = (const float*)d_in[6];
  const float* ab1   = (const float*)d_in[7];
  const float* aw2   = (const float*)d_in[8];
  const float* gam   = (const float*)d_in[9];
  const float* bet   = (const float*)d_in[10];
  const float* flog  = (const float*)d_in[11];
  const float* clsW  = (const float*)d_in[12];
  const float* clsB  = (const float*)d_in[13];
  float* out = (float*)d_out;

  char* wsp = (char*)d_ws;
  size_t o = 0;
  auto alloc = [&](size_t b)->char*{ char* p = wsp + o; o = (o + b + 255) & ~(size_t)255; return p; };
  u16*  xb16  = (u16*) alloc((size_t)N_NODES*128*2);
  u16*  S     = (u16*) alloc((size_t)N_NODES*128*2);
  u16*  P1    = (u16*) alloc((size_t)N_NODES*128*2);
  u16*  Pd    = (u16*) alloc((size_t)N_NODES*128*2);
  u16*  SAb   = (u16*) alloc((size_t)N_NODES*16*2);
  u16*  P1A   = (u16*) alloc((size_t)N_NODES*16*2);
  u16*  PdA   = (u16*) alloc((size_t)N_NODES*16*2);
  u16*  WT    = (u16*) alloc((size_t)LL*NCOLS*128*2);
  float* bsA  = (float*)alloc(LL*16*4);
  float* bcA  = (float*)alloc(LL*16*4);
  int* bsum   = (int*) alloc((size_t)2*SCAN_NB*4);
  int* degO   = (int*) alloc((size_t)N_NODES*4);
  int* degI   = (int*) alloc((size_t)N_NODES*4);
  int* cursO  = (int*) alloc((size_t)N_NODES*4);
  int* cursI  = (int*) alloc((size_t)N_NODES*4);
  int* offO   = (int*) alloc((size_t)(N_NODES+1)*4);
  int* offI   = (int*) alloc((size_t)(N_NODES+1)*4);
  int* csrO   = (int*) alloc((size_t)N_EDGES*4);
  int* csrI   = (int*) alloc((size_t)N_EDGES*4);

  if (ws_size < o){
    k_fail<<<(N_NODES*2+255)/256, 256, 0, stream>>>(out);
    return;
  }

  (void)hipMemsetAsync(degO, 0, (size_t)((char*)offO - (char*)degO), stream);

  k_cvt<<<(N_NODES*DD+255)/256, 256, 0, stream>>>(X0, xb16);
  k_hist<<<(N_EDGES+255)/256, 256, 0, stream>>>(EI, degO, degI);
  k_scan1<<<dim3(SCAN_NB,2), SCAN_B, 0, stream>>>(degO, degI, bsum);
  k_scan2<<<1, 64, 0, stream>>>(bsum, offO, offI);
  k_scan3<<<dim3(SCAN_NB,2), SCAN_B, 0, stream>>>(degO, degI, bsum, offO, offI);
  k_scatter<<<(N_EDGES+255)/256, 256, 0, stream>>>(EI, offO, offI, cursO, cursI, csrO, csrI);
  k_pack_wt<<<(LL*NCOLS*128+255)/256, 256, 0, stream>>>(Wself, Wctx, A1, WT);
  k_pack_bias<<<1, 128, 0, stream>>>(bs, bc, A1, bsA, bcA);

  GemmOut go{S, P1, Pd, SAb, P1A, PdA};
  const int gemm_blocks = ((N_NODES/16) + 3) / 4;
  for (int l = 0; l < LL; ++l){
    k_gemm<<<gemm_blocks, 256, 0, stream>>>(xb16, WT + (size_t)l*NCOLS*128, go);
    k_aggepi<<<N_NODES/4, 256, 0, stream>>>(l, S, P1, Pd, SAb, P1A, PdA,
                                            offO, offI, csrO, csrI,
                                            bs, bc, bsA, bcA, ab1, aw2,
                                            gam, bet, flog, xb16,
                                            clsW, clsB, out);
  }
}

// Round 10
// 812.340 us; speedup vs baseline: 1.6177x; 1.0626x over previous
//
#include <hip/hip_runtime.h>

#define N_NODES 50000
#define N_EDGES 800000
#define DD 128
#define HH 128
#define LL 4
#define AHH 16
#define LN_EPS 1e-5f
#define NCOLS 432   // 128 S | 128 P1 | 128 Pd | 16 SA | 16 P1A | 16 PdA
#define SCAN_B 512
#define SCAN_NB ((N_NODES + SCAN_B - 1) / SCAN_B)
#define WTPAD 136

typedef unsigned short u16;
typedef unsigned int u32;
typedef __attribute__((ext_vector_type(8))) short short8;
typedef __attribute__((ext_vector_type(4))) float f32x4;

__device__ __forceinline__ float bf2f(u16 h){
  u32 u = ((u32)h) << 16;
  return __builtin_bit_cast(float, u);
}
__device__ __forceinline__ float bflo(u32 v){ return __builtin_bit_cast(float, v << 16); }
__device__ __forceinline__ float bfhi(u32 v){ return __builtin_bit_cast(float, v & 0xffff0000u); }
__device__ __forceinline__ u16 f2bf(float x){
  u32 u = __builtin_bit_cast(u32, x);
  u += 0x7fffu + ((u >> 16) & 1u);
  return (u16)(u >> 16);
}

// ---------------- sentinel (workspace too small) ----------------
__global__ void k_fail(float* out){
  int i = blockIdx.x*256 + threadIdx.x;
  if (i < N_NODES*2) out[i] = 1.0e6f;
}

// ---------------- f32 -> bf16 conversion of node features ----------------
__global__ void k_cvt(const float* __restrict__ X, u16* __restrict__ Xb){
  int i = blockIdx.x*256 + threadIdx.x;
  if (i < N_NODES*DD) Xb[i] = f2bf(X[i]);
}

// ---------------- CSR build ----------------
__global__ void k_hist(const int* __restrict__ ei, int* degO, int* degI){
  int e = blockIdx.x*256 + threadIdx.x;
  if (e >= N_EDGES) return;
  atomicAdd(&degO[ei[N_EDGES + e]], 1);  // tgt histogram (outgoing view)
  atomicAdd(&degI[ei[e]], 1);            // src histogram (incoming view)
}

// 3-phase parallel exclusive scan
__global__ __launch_bounds__(SCAN_B) void k_scan1(const int* __restrict__ degO,
                                                  const int* __restrict__ degI, int* bsum){
  int b = blockIdx.x, t = threadIdx.x;
  const int* deg = blockIdx.y ? degI : degO;
  int i = b*SCAN_B + t;
  int v = (i < N_NODES) ? deg[i] : 0;
  #pragma unroll
  for (int m = 1; m < 64; m <<= 1) v += __shfl_xor(v, m);
  __shared__ int ws[SCAN_B/64];
  if ((t & 63) == 0) ws[t >> 6] = v;
  __syncthreads();
  if (t == 0){
    int s = 0;
    for (int w = 0; w < SCAN_B/64; ++w) s += ws[w];
    bsum[blockIdx.y*SCAN_NB + b] = s;
  }
}
__global__ void k_scan2(int* bsum, int* offO, int* offI){
  if (threadIdx.x == 0){
    int run = 0;
    for (int i = 0; i < SCAN_NB; ++i){ int v = bsum[i]; bsum[i] = run; run += v; }
    offO[N_NODES] = run;
    run = 0;
    for (int i = 0; i < SCAN_NB; ++i){ int v = bsum[SCAN_NB+i]; bsum[SCAN_NB+i] = run; run += v; }
    offI[N_NODES] = run;
  }
}
__global__ __launch_bounds__(SCAN_B) void k_scan3(const int* __restrict__ degO,
                                                  const int* __restrict__ degI,
                                                  const int* __restrict__ bsum,
                                                  int* offO, int* offI){
  int b = blockIdx.x, t = threadIdx.x, lane = t & 63, w = t >> 6;
  const int* deg = blockIdx.y ? degI : degO;
  int* off = blockIdx.y ? offI : offO;
  int i = b*SCAN_B + t;
  int v = (i < N_NODES) ? deg[i] : 0;
  int x = v;
  #pragma unroll
  for (int m = 1; m < 64; m <<= 1){ int tt = __shfl_up(x, m); if (lane >= m) x += tt; }
  __shared__ int ws[SCAN_B/64];
  if (lane == 63) ws[w] = x;
  __syncthreads();
  int woff = 0;
  for (int k = 0; k < w; ++k) woff += ws[k];
  if (i < N_NODES) off[i] = bsum[blockIdx.y*SCAN_NB + b] + woff + x - v;
}

__global__ void k_scatter(const int* __restrict__ ei, const int* __restrict__ offO,
                          const int* __restrict__ offI, int* cursO, int* cursI,
                          int* csrO, int* csrI){
  int e = blockIdx.x*256 + threadIdx.x;
  if (e >= N_EDGES) return;
  int s = ei[e], t = ei[N_EDGES + e];
  int p = atomicAdd(&cursO[t], 1); csrO[offO[t] + p] = s;
  int q = atomicAdd(&cursI[s], 1); csrI[offI[s] + q] = t;
}

// ---------------- weight packing (f32 sources -> bf16 WT) ----------------
__global__ void k_pack_wt(const float* __restrict__ Wself, const float* __restrict__ Wctx,
                          const float* __restrict__ A1, u16* __restrict__ WT){
  int idx = blockIdx.x*256 + threadIdx.x;
  if (idx >= LL*NCOLS*DD) return;
  int k = idx & 127;
  int j = (idx >> 7) % NCOLS;
  int l = idx / (NCOLS*DD);
  const float* Ws = Wself + (size_t)l*DD*HH;
  const float* Wc = Wctx + (size_t)l*2*DD*HH;
  const float* A  = A1 + (size_t)l*HH*AHH;
  float v = 0.f;
  if (j < 128) v = Ws[k*HH + j];
  else if (j < 256) v = Wc[k*HH + (j-128)];
  else if (j < 384) v = Wc[(128+k)*HH + (j-256)] - Wc[k*HH + (j-256)];
  else if (j < 400){ int a = j-384; for (int h=0; h<HH; ++h) v += Ws[k*HH+h] * A[h*AHH+a]; }
  else if (j < 416){ int a = j-400; for (int h=0; h<HH; ++h) v += Wc[k*HH+h] * A[h*AHH+a]; }
  else { int a = j-416; for (int h=0; h<HH; ++h) v += (Wc[(128+k)*HH+h] - Wc[k*HH+h]) * A[h*AHH+a]; }
  WT[((size_t)l*NCOLS + j)*DD + k] = f2bf(v);
}

__global__ void k_pack_bias(const float* __restrict__ bs, const float* __restrict__ bc,
                            const float* __restrict__ A1, float* bsA, float* bcA){
  int i = threadIdx.x;
  if (i >= LL*2*AHH) return;
  int l = i >> 5, which = (i >> 4) & 1, a = i & 15;
  const float* b = which ? (bc + l*HH) : (bs + l*HH);
  const float* A = A1 + (size_t)l*HH*AHH;
  float v = 0.f;
  for (int h = 0; h < HH; ++h) v += b[h] * A[h*AHH + a];
  (which ? bcA : bsA)[l*AHH + a] = v;
}

// ---------------- fused GEMM: 3-tile LDS staging, 9 stages (18 barriers) ----------------
struct GemmOut { u16 *S, *P1, *Pd, *SA, *P1A, *PdA; };

__global__ __launch_bounds__(256) void k_gemm(const u16* __restrict__ X,
                                              const u16* __restrict__ WT, GemmOut o){
  __shared__ u16 lw[3*16*WTPAD];
  int tid = threadIdx.x;
  int wid = tid >> 6, lane = tid & 63;
  int m0 = (blockIdx.x*4 + wid)*16;
  bool mvalid = (m0 < N_NODES);
  int m0c = mvalid ? m0 : (N_NODES - 16);
  int l15 = lane & 15, quad = lane >> 4;
  int sr = tid >> 4, sp = tid & 15;   // staging: tile-row sr, 8-u16 part sp (per tile)

  f32x4 acc[27];
  #pragma unroll
  for (int j = 0; j < 27; ++j) acc[j] = (f32x4){0.f,0.f,0.f,0.f};

  const u16* xr = X + (size_t)(m0c + l15)*DD + quad*8;
  short8 a[4];
  #pragma unroll
  for (int ks = 0; ks < 4; ++ks) a[ks] = *(const short8*)(xr + ks*32);

  short8 st[3];
  #pragma unroll
  for (int k = 0; k < 3; ++k)
    st[k] = *(const short8*)(WT + ((size_t)k*16 + sr)*DD + sp*8);   // prefetch stage 0

  for (int stage = 0; stage < 9; ++stage){
    int jbase = stage*3;
    __syncthreads();   // prior stage's LDS reads done
    #pragma unroll
    for (int k = 0; k < 3; ++k)
      *(short8*)(&lw[(k*16 + sr)*WTPAD + sp*8]) = st[k];
    __syncthreads();   // stage visible
    if (stage < 8){
      #pragma unroll
      for (int k = 0; k < 3; ++k)
        st[k] = *(const short8*)(WT + ((size_t)(jbase+3+k)*16 + sr)*DD + sp*8);
    }
    #pragma unroll
    for (int k = 0; k < 3; ++k){
      const u16* wb = &lw[(k*16 + l15)*WTPAD + quad*8];
      #pragma unroll
      for (int ks = 0; ks < 4; ++ks){
        short8 b = *(const short8*)(wb + ks*32);
        acc[jbase+k] = __builtin_amdgcn_mfma_f32_16x16x32_bf16(a[ks], b, acc[jbase+k], 0, 0, 0);
      }
    }
  }
  if (!mvalid) return;
  #pragma unroll
  for (int j = 0; j < 27; ++j){
    int col = j*16 + l15;
    #pragma unroll
    for (int r = 0; r < 4; ++r){
      int row = m0 + quad*4 + r;
      u16 hv = f2bf(acc[j][r]);
      if (col < 128)      o.S  [(size_t)row*128 + col]       = hv;
      else if (col < 256) o.P1 [(size_t)row*128 + col - 128] = hv;
      else if (col < 384) o.Pd [(size_t)row*128 + col - 256] = hv;
      else if (col < 400) o.SA [(size_t)row*16  + col - 384] = hv;
      else if (col < 416) o.P1A[(size_t)row*16  + col - 400] = hv;
      else                o.PdA[(size_t)row*16  + col - 416] = hv;
    }
  }
}

// ------- fused CSR gather (half-wave dwordx2) + attention + LN + residual + classifier -------
__global__ __launch_bounds__(256) void k_aggepi(int l,
  const u16* __restrict__ S, const u16* __restrict__ P1,
  const u16* __restrict__ Pd, const u16* __restrict__ SA,
  const u16* __restrict__ P1A, const u16* __restrict__ PdA,
  const int* __restrict__ offO, const int* __restrict__ offI,
  const int* __restrict__ csrO, const int* __restrict__ csrI,
  const float* __restrict__ b_self, const float* __restrict__ b_ctx,
  const float* __restrict__ bsA, const float* __restrict__ bcA,
  const float* __restrict__ att_b1, const float* __restrict__ att_w2,
  const float* __restrict__ gamma, const float* __restrict__ beta,
  const float* __restrict__ flog,
  u16* __restrict__ xb16,
  const float* __restrict__ clsW, const float* __restrict__ clsB,
  float* __restrict__ out)
{
  int n = (blockIdx.x * 256 + threadIdx.x) >> 6;
  int lane = threadIdx.x & 63;
  int f0 = lane * 2;
  // half-wave gather layout: half h handles edges (pair_base + h); sub-lane s
  // covers features 4s..4s+3 (8 bytes at offset 8s of each 256B Pd row)
  int h = lane >> 5, s5 = lane & 31;
  const u16* PdH = Pd + 4*s5;

  int begO = offO[n], endO = offO[n+1];
  int begI = offI[n], endI = offI[n+1];

  float oa0=0.f,oa1=0.f,oa2=0.f,oa3=0.f, ob0=0.f,ob1=0.f,ob2=0.f,ob3=0.f;
  float ia0=0.f,ia1=0.f,ia2=0.f,ia3=0.f, ib0=0.f,ib1=0.f,ib2=0.f,ib3=0.f;

  int eO = begO, eI = begI;
  // fused main loop: 2 O-pairs + 2 I-pairs per iteration (8 row-loads in flight)
  for (; eO + 4 <= endO && eI + 4 <= endI; eO += 4, eI += 4){
    int nO0 = csrO[eO + h],     nO1 = csrO[eO + 2 + h];
    int nI0 = csrI[eI + h],     nI1 = csrI[eI + 2 + h];
    uint2 vO0 = *(const uint2*)(PdH + (size_t)nO0*128);
    uint2 vO1 = *(const uint2*)(PdH + (size_t)nO1*128);
    uint2 vI0 = *(const uint2*)(PdH + (size_t)nI0*128);
    uint2 vI1 = *(const uint2*)(PdH + (size_t)nI1*128);
    oa0 += bflo(vO0.x); oa1 += bfhi(vO0.x); oa2 += bflo(vO0.y); oa3 += bfhi(vO0.y);
    ob0 += bflo(vO1.x); ob1 += bfhi(vO1.x); ob2 += bflo(vO1.y); ob3 += bfhi(vO1.y);
    ia0 += bflo(vI0.x); ia1 += bfhi(vI0.x); ia2 += bflo(vI0.y); ia3 += bfhi(vI0.y);
    ib0 += bflo(vI1.x); ib1 += bfhi(vI1.x); ib2 += bflo(vI1.y); ib3 += bfhi(vI1.y);
  }
  // drain O pairs
  for (; eO + 2 <= endO; eO += 2){
    int nb = csrO[eO + h];
    uint2 v = *(const uint2*)(PdH + (size_t)nb*128);
    oa0 += bflo(v.x); oa1 += bfhi(v.x); oa2 += bflo(v.y); oa3 += bfhi(v.y);
  }
  if (eO < endO && h == 0){   // odd leftover: half 0 only
    int nb = csrO[eO];
    uint2 v = *(const uint2*)(PdH + (size_t)nb*128);
    oa0 += bflo(v.x); oa1 += bfhi(v.x); oa2 += bflo(v.y); oa3 += bfhi(v.y);
  }
  // drain I pairs
  for (; eI + 2 <= endI; eI += 2){
    int nb = csrI[eI + h];
    uint2 v = *(const uint2*)(PdH + (size_t)nb*128);
    ia0 += bflo(v.x); ia1 += bfhi(v.x); ia2 += bflo(v.y); ia3 += bfhi(v.y);
  }
  if (eI < endI && h == 0){
    int nb = csrI[eI];
    uint2 v = *(const uint2*)(PdH + (size_t)nb*128);
    ia0 += bflo(v.x); ia1 += bfhi(v.x); ia2 += bflo(v.y); ia3 += bfhi(v.y);
  }
  oa0 += ob0; oa1 += ob1; oa2 += ob2; oa3 += ob3;
  ia0 += ib0; ia1 += ib1; ia2 += ib2; ia3 += ib3;
  // cross-half combine: full sums for features 4*s5..4*s5+3
  oa0 += __shfl_xor(oa0, 32); oa1 += __shfl_xor(oa1, 32);
  oa2 += __shfl_xor(oa2, 32); oa3 += __shfl_xor(oa3, 32);
  ia0 += __shfl_xor(ia0, 32); ia1 += __shfl_xor(ia1, 32);
  ia2 += __shfl_xor(ia2, 32); ia3 += __shfl_xor(ia3, 32);
  // redistribute to 2-feats/lane: feature 2*lane is at lane>>1, element 2*(lane&1)
  {
    int src = lane >> 1;
    float t0 = __shfl(oa0, src), t1 = __shfl(oa1, src), t2 = __shfl(oa2, src), t3 = __shfl(oa3, src);
    float u0 = __shfl(ia0, src), u1 = __shfl(ia1, src), u2 = __shfl(ia2, src), u3 = __shfl(ia3, src);
    int odd = lane & 1;
    oa0 = odd ? t2 : t0;  oa1 = odd ? t3 : t1;
    ia0 = odd ? u2 : u0;  ia1 = odd ? u3 : u1;
  }
  float ao0 = oa0, ao1 = oa1, ai0 = ia0, ai1 = ia1;

  // --- PdA gathers: 4 edges per iteration via the four 16-lane groups ---
  int a16 = lane & 15, g = lane >> 4;
  float aoa = 0.f, aia = 0.f;
  for (int e2 = begO + g; e2 < endO; e2 += 4)
    aoa += bf2f(PdA[(size_t)csrO[e2]*16 + a16]);
  for (int e2 = begI + g; e2 < endI; e2 += 4)
    aia += bf2f(PdA[(size_t)csrI[e2]*16 + a16]);
  aoa += __shfl_xor(aoa, 16); aoa += __shfl_xor(aoa, 32);
  aia += __shfl_xor(aia, 16); aia += __shfl_xor(aia, 32);

  float dO = (float)(endO - begO), dI = (float)(endI - begI);

  // --- three views, 2 features per lane ---
  u32 sv = *(const u32*)(S  + (size_t)n*128 + f0);
  u32 pv = *(const u32*)(P1 + (size_t)n*128 + f0);
  float2 bsv = *(const float2*)(b_self + l*128 + f0);
  float2 bcv = *(const float2*)(b_ctx  + l*128 + f0);
  float p10 = bflo(pv), p11 = bfhi(pv);
  float mv00 = bflo(sv) + bsv.x;
  float mv01 = bfhi(sv) + bsv.y;
  float mv10 = dO*p10 + ao0 + bcv.x, mv11 = dO*p11 + ao1 + bcv.y;
  float mv20 = dI*p10 + ai0 + bcv.x, mv21 = dI*p11 + ai1 + bcv.y;

  // --- attention: lanes [v*16 + a], v<3 compute tanh(t + b1)*w2, reduce over a ---
  int a = a16, v = g;
  float u = 0.f;
  if (v < 3){
    float t;
    if (v == 0)      t = bf2f(SA[(size_t)n*16 + a]) + bsA[l*16 + a];
    else if (v == 1) t = dO*bf2f(P1A[(size_t)n*16 + a]) + aoa + bcA[l*16 + a];
    else             t = dI*bf2f(P1A[(size_t)n*16 + a]) + aia + bcA[l*16 + a];
    u = tanhf(t + att_b1[l*16 + a]) * att_w2[l*16 + a];
  }
  u += __shfl_xor(u, 1); u += __shfl_xor(u, 2);
  u += __shfl_xor(u, 4); u += __shfl_xor(u, 8);
  float s0 = __shfl(u, 0), s1 = __shfl(u, 16), s2 = __shfl(u, 32);
  float mx = fmaxf(s0, fmaxf(s1, s2));
  float e0 = __expf(s0-mx), e1 = __expf(s1-mx), e2 = __expf(s2-mx);
  float inv = 1.f / (e0 + e1 + e2);
  float w0 = e0*inv, w1 = e1*inv, w2v = e2*inv;
  float h0 = w0*mv00 + w1*mv10 + w2v*mv20;
  float h1 = w0*mv01 + w1*mv11 + w2v*mv21;

  // --- layer norm over 128 ---
  float sum = h0 + h1, sq = h0*h0 + h1*h1;
  #pragma unroll
  for (int m = 1; m < 64; m <<= 1){ sum += __shfl_xor(sum, m); sq += __shfl_xor(sq, m); }
  float mu = sum * (1.f/128.f);
  float var = sq * (1.f/128.f) - mu*mu;
  float rs = rsqrtf(var + LN_EPS);
  float2 gv = *(const float2*)(gamma + l*128 + f0);
  float2 bv = *(const float2*)(beta  + l*128 + f0);
  float y0 = fmaxf((h0 - mu)*rs*gv.x + bv.x, 0.f);
  float y1 = fmaxf((h1 - mu)*rs*gv.y + bv.y, 0.f);
  float xn0 = y0, xn1 = y1;
  if (l > 0){
    u32 xv = *(const u32*)(xb16 + (size_t)n*128 + f0);
    xn0 += bflo(xv); xn1 += bfhi(xv);
  }
  // bf16 residual stream (also next layer's GEMM input)
  *(u32*)(xb16 + (size_t)n*128 + f0) = (u32)f2bf(xn0) | ((u32)f2bf(xn1) << 16);

  // fusion weight (softmax over 4 logits)
  float g0 = flog[0], g1 = flog[1], g2 = flog[2], g3 = flog[3];
  float gm = fmaxf(fmaxf(g0,g1), fmaxf(g2,g3));
  float q0 = __expf(g0-gm), q1 = __expf(g1-gm), q2 = __expf(g2-gm), q3 = __expf(g3-gm);
  float fwl = (l==0?q0 : l==1?q1 : l==2?q2 : q3) / (q0+q1+q2+q3);

  // classifier accumulate: out[n,:] += fwl * (x_l[n] @ clsW); bias at last layer
  float4 w = *(const float4*)(clsW + lane*4);   // rows 2*lane, 2*lane+1 of [128,2]
  float o0 = xn0*w.x + xn1*w.z;
  float o1 = xn0*w.y + xn1*w.w;
  #pragma unroll
  for (int m = 1; m < 64; m <<= 1){ o0 += __shfl_xor(o0, m); o1 += __shfl_xor(o1, m); }
  if (lane == 0){
    float2* op = (float2*)(out + (size_t)n*2);
    float2 prev = (l > 0) ? *op : make_float2(0.f, 0.f);
    float r0 = prev.x + fwl*o0, r1 = prev.y + fwl*o1;
    if (l == LL-1){ r0 += clsB[0]; r1 += clsB[1]; }
    *op = make_float2(r0, r1);
  }
}

extern "C" void kernel_launch(void* const* d_in, const int* in_sizes, int n_in,
                              void* d_out, int out_size, void* d_ws, size_t ws_size,
                              hipStream_t stream){
  const float* X0    = (const float*)d_in[0];
  const int*   EI    = (const int*)d_in[1];
  const float* Wself = (const float*)d_in[2];
  const float* bs    = (const float*)d_in[3];
  const float* Wctx  = (const float*)d_in[4];
  const float* bc    = (const float*)d_in[5];
  const float* A1    = (const float*)d_in[6];
  const float* ab1   = (const float*)d_in[7];
  const float* aw2   = (const float*)d_in[8];
  const float* gam   = (const float*)d_in[9];
  const float* bet   = (const float*)d_in[10];
  const float* flog  = (const float*)d_in[11];
  const float* clsW  = (const float*)d_in[12];
  const float* clsB  = (const float*)d_in[13];
  float* out = (float*)d_out;

  char* wsp = (char*)d_ws;
  size_t o = 0;
  auto alloc = [&](size_t b)->char*{ char* p = wsp + o; o = (o + b + 255) & ~(size_t)255; return p; };
  u16*  xb16  = (u16*) alloc((size_t)N_NODES*128*2);
  u16*  S     = (u16*) alloc((size_t)N_NODES*128*2);
  u16*  P1    = (u16*) alloc((size_t)N_NODES*128*2);
  u16*  Pd    = (u16*) alloc((size_t)N_NODES*128*2);
  u16*  SAb   = (u16*) alloc((size_t)N_NODES*16*2);
  u16*  P1A   = (u16*) alloc((size_t)N_NODES*16*2);
  u16*  PdA   = (u16*) alloc((size_t)N_NODES*16*2);
  u16*  WT    = (u16*) alloc((size_t)LL*NCOLS*128*2);
  float* bsA  = (float*)alloc(LL*16*4);
  float* bcA  = (float*)alloc(LL*16*4);
  int* bsum   = (int*) alloc((size_t)2*SCAN_NB*4);
  int* degO   = (int*) alloc((size_t)N_NODES*4);
  int* degI   = (int*) alloc((size_t)N_NODES*4);
  int* cursO  = (int*) alloc((size_t)N_NODES*4);
  int* cursI  = (int*) alloc((size_t)N_NODES*4);
  int* offO   = (int*) alloc((size_t)(N_NODES+1)*4);
  int* offI   = (int*) alloc((size_t)(N_NODES+1)*4);
  int* csrO   = (int*) alloc((size_t)N_EDGES*4);
  int* csrI   = (int*) alloc((size_t)N_EDGES*4);

  if (ws_size < o){
    k_fail<<<(N_NODES*2+255)/256, 256, 0, stream>>>(out);
    return;
  }

  (void)hipMemsetAsync(degO, 0, (size_t)((char*)offO - (char*)degO), stream);

  k_cvt<<<(N_NODES*DD+255)/256, 256, 0, stream>>>(X0, xb16);
  k_hist<<<(N_EDGES+255)/256, 256, 0, stream>>>(EI, degO, degI);
  k_scan1<<<dim3(SCAN_NB,2), SCAN_B, 0, stream>>>(degO, degI, bsum);
  k_scan2<<<1, 64, 0, stream>>>(bsum, offO, offI);
  k_scan3<<<dim3(SCAN_NB,2), SCAN_B, 0, stream>>>(degO, degI, bsum, offO, offI);
  k_scatter<<<(N_EDGES+255)/256, 256, 0, stream>>>(EI, offO, offI, cursO, cursI, csrO, csrI);
  k_pack_wt<<<(LL*NCOLS*128+255)/256, 256, 0, stream>>>(Wself, Wctx, A1, WT);
  k_pack_bias<<<1, 128, 0, stream>>>(bs, bc, A1, bsA, bcA);

  GemmOut go{S, P1, Pd, SAb, P1A, PdA};
  const int gemm_blocks = ((N_NODES/16) + 3) / 4;
  for (int l = 0; l < LL; ++l){
    k_gemm<<<gemm_blocks, 256, 0, stream>>>(xb16, WT + (size_t)l*NCOLS*128, go);
    k_aggepi<<<N_NODES/4, 256, 0, stream>>>(l, S, P1, Pd, SAb, P1A, PdA,
                                            offO, offI, csrO, csrI,
                                            bs, bc, bsA, bcA, ab1, aw2,
                                            gam, bet, flog, xb16,
                                            clsW, clsB, out);
  }
}

// Round 11
// 768.730 us; speedup vs baseline: 1.7095x; 1.0567x over previous
//
#include <hip/hip_runtime.h>

#define N_NODES 50000
#define N_EDGES 800000
#define DD 128
#define HH 128
#define LL 4
#define AHH 16
#define LN_EPS 1e-5f
#define NCOLS 432   // 128 S | 128 P1 | 128 Pd | 16 SA | 16 P1A | 16 PdA
#define SCAN_B 512
#define SCAN_NB ((N_NODES + SCAN_B - 1) / SCAN_B)
#define WTPAD 136
#define WT_BLOCKS ((LL*NCOLS*DD)/256)   // 864, exact

typedef unsigned short u16;
typedef unsigned int u32;
typedef __attribute__((ext_vector_type(8))) short short8;
typedef __attribute__((ext_vector_type(4))) float f32x4;

__device__ __forceinline__ float bf2f(u16 h){
  u32 u = ((u32)h) << 16;
  return __builtin_bit_cast(float, u);
}
__device__ __forceinline__ float bflo(u32 v){ return __builtin_bit_cast(float, v << 16); }
__device__ __forceinline__ float bfhi(u32 v){ return __builtin_bit_cast(float, v & 0xffff0000u); }
__device__ __forceinline__ u16 f2bf(float x){
  u32 u = __builtin_bit_cast(u32, x);
  u += 0x7fffu + ((u >> 16) & 1u);
  return (u16)(u >> 16);
}

// ---------------- sentinel (workspace too small) ----------------
__global__ void k_fail(float* out){
  int i = blockIdx.x*256 + threadIdx.x;
  if (i < N_NODES*2) out[i] = 1.0e6f;
}

// ---------------- fused: f32->bf16 conversion + degree histograms ----------------
__global__ __launch_bounds__(256) void k_cvt_hist(const float* __restrict__ X,
    u16* __restrict__ Xb, const int* __restrict__ ei, int* degO, int* degI){
  int i = blockIdx.x*256 + threadIdx.x;
  if (i < N_NODES*DD) Xb[i] = f2bf(X[i]);
  if (i < N_EDGES){
    atomicAdd(&degO[ei[N_EDGES + i]], 1);  // tgt histogram (outgoing view)
    atomicAdd(&degI[ei[i]], 1);            // src histogram (incoming view)
  }
}

// 3-phase parallel exclusive scan
__global__ __launch_bounds__(SCAN_B) void k_scan1(const int* __restrict__ degO,
                                                  const int* __restrict__ degI, int* bsum){
  int b = blockIdx.x, t = threadIdx.x;
  const int* deg = blockIdx.y ? degI : degO;
  int i = b*SCAN_B + t;
  int v = (i < N_NODES) ? deg[i] : 0;
  #pragma unroll
  for (int m = 1; m < 64; m <<= 1) v += __shfl_xor(v, m);
  __shared__ int ws[SCAN_B/64];
  if ((t & 63) == 0) ws[t >> 6] = v;
  __syncthreads();
  if (t == 0){
    int s = 0;
    for (int w = 0; w < SCAN_B/64; ++w) s += ws[w];
    bsum[blockIdx.y*SCAN_NB + b] = s;
  }
}
__global__ void k_scan2(int* bsum, int* offO, int* offI){
  if (threadIdx.x == 0){
    int run = 0;
    for (int i = 0; i < SCAN_NB; ++i){ int v = bsum[i]; bsum[i] = run; run += v; }
    offO[N_NODES] = run;
    run = 0;
    for (int i = 0; i < SCAN_NB; ++i){ int v = bsum[SCAN_NB+i]; bsum[SCAN_NB+i] = run; run += v; }
    offI[N_NODES] = run;
  }
}
__global__ __launch_bounds__(SCAN_B) void k_scan3(const int* __restrict__ degO,
                                                  const int* __restrict__ degI,
                                                  const int* __restrict__ bsum,
                                                  int* offO, int* offI){
  int b = blockIdx.x, t = threadIdx.x, lane = t & 63, w = t >> 6;
  const int* deg = blockIdx.y ? degI : degO;
  int* off = blockIdx.y ? offI : offO;
  int i = b*SCAN_B + t;
  int v = (i < N_NODES) ? deg[i] : 0;
  int x = v;
  #pragma unroll
  for (int m = 1; m < 64; m <<= 1){ int tt = __shfl_up(x, m); if (lane >= m) x += tt; }
  __shared__ int ws[SCAN_B/64];
  if (lane == 63) ws[w] = x;
  __syncthreads();
  int woff = 0;
  for (int k = 0; k < w; ++k) woff += ws[k];
  if (i < N_NODES) off[i] = bsum[blockIdx.y*SCAN_NB + b] + woff + x - v;
}

__global__ void k_scatter(const int* __restrict__ ei, const int* __restrict__ offO,
                          const int* __restrict__ offI, int* cursO, int* cursI,
                          int* csrO, int* csrI){
  int e = blockIdx.x*256 + threadIdx.x;
  if (e >= N_EDGES) return;
  int s = ei[e], t = ei[N_EDGES + e];
  int p = atomicAdd(&cursO[t], 1); csrO[offO[t] + p] = s;
  int q = atomicAdd(&cursI[s], 1); csrI[offI[s] + q] = t;
}

// ---------------- fused weight+bias packing (f32 sources -> bf16 WT, f32 bsA/bcA) ----------------
__global__ void k_pack(const float* __restrict__ Wself, const float* __restrict__ Wctx,
                       const float* __restrict__ A1, const float* __restrict__ bs,
                       const float* __restrict__ bc, u16* __restrict__ WT,
                       float* bsA, float* bcA){
  if (blockIdx.x == WT_BLOCKS){
    int i = threadIdx.x;
    if (i < LL*2*AHH){
      int l = i >> 5, which = (i >> 4) & 1, a = i & 15;
      const float* b = which ? (bc + l*HH) : (bs + l*HH);
      const float* A = A1 + (size_t)l*HH*AHH;
      float v = 0.f;
      for (int h = 0; h < HH; ++h) v += b[h] * A[h*AHH + a];
      (which ? bcA : bsA)[l*AHH + a] = v;
    }
    return;
  }
  int idx = blockIdx.x*256 + threadIdx.x;
  int k = idx & 127;
  int j = (idx >> 7) % NCOLS;
  int l = idx / (NCOLS*DD);
  const float* Ws = Wself + (size_t)l*DD*HH;
  const float* Wc = Wctx + (size_t)l*2*DD*HH;
  const float* A  = A1 + (size_t)l*HH*AHH;
  float v = 0.f;
  if (j < 128) v = Ws[k*HH + j];
  else if (j < 256) v = Wc[k*HH + (j-128)];
  else if (j < 384) v = Wc[(128+k)*HH + (j-256)] - Wc[k*HH + (j-256)];
  else if (j < 400){ int a = j-384; for (int h=0; h<HH; ++h) v += Ws[k*HH+h] * A[h*AHH+a]; }
  else if (j < 416){ int a = j-400; for (int h=0; h<HH; ++h) v += Wc[k*HH+h] * A[h*AHH+a]; }
  else { int a = j-416; for (int h=0; h<HH; ++h) v += (Wc[(128+k)*HH+h] - Wc[k*HH+h]) * A[h*AHH+a]; }
  WT[((size_t)l*NCOLS + j)*DD + k] = f2bf(v);
}

// ---------------- fused GEMM: 3-tile LDS staging, 9 stages (18 barriers) ----------------
struct GemmOut { u16 *S, *P1, *Pd, *SA, *P1A, *PdA; };

__global__ __launch_bounds__(256) void k_gemm(const u16* __restrict__ X,
                                              const u16* __restrict__ WT, GemmOut o){
  __shared__ u16 lw[3*16*WTPAD];
  int tid = threadIdx.x;
  int wid = tid >> 6, lane = tid & 63;
  int m0 = (blockIdx.x*4 + wid)*16;
  bool mvalid = (m0 < N_NODES);
  int m0c = mvalid ? m0 : (N_NODES - 16);
  int l15 = lane & 15, quad = lane >> 4;
  int sr = tid >> 4, sp = tid & 15;   // staging: tile-row sr, 8-u16 part sp (per tile)

  f32x4 acc[27];
  #pragma unroll
  for (int j = 0; j < 27; ++j) acc[j] = (f32x4){0.f,0.f,0.f,0.f};

  const u16* xr = X + (size_t)(m0c + l15)*DD + quad*8;
  short8 a[4];
  #pragma unroll
  for (int ks = 0; ks < 4; ++ks) a[ks] = *(const short8*)(xr + ks*32);

  short8 st[3];
  #pragma unroll
  for (int k = 0; k < 3; ++k)
    st[k] = *(const short8*)(WT + ((size_t)k*16 + sr)*DD + sp*8);   // prefetch stage 0

  for (int stage = 0; stage < 9; ++stage){
    int jbase = stage*3;
    __syncthreads();   // prior stage's LDS reads done
    #pragma unroll
    for (int k = 0; k < 3; ++k)
      *(short8*)(&lw[(k*16 + sr)*WTPAD + sp*8]) = st[k];
    __syncthreads();   // stage visible
    if (stage < 8){
      #pragma unroll
      for (int k = 0; k < 3; ++k)
        st[k] = *(const short8*)(WT + ((size_t)(jbase+3+k)*16 + sr)*DD + sp*8);
    }
    #pragma unroll
    for (int k = 0; k < 3; ++k){
      const u16* wb = &lw[(k*16 + l15)*WTPAD + quad*8];
      #pragma unroll
      for (int ks = 0; ks < 4; ++ks){
        short8 b = *(const short8*)(wb + ks*32);
        acc[jbase+k] = __builtin_amdgcn_mfma_f32_16x16x32_bf16(a[ks], b, acc[jbase+k], 0, 0, 0);
      }
    }
  }
  if (!mvalid) return;
  #pragma unroll
  for (int j = 0; j < 27; ++j){
    int col = j*16 + l15;
    #pragma unroll
    for (int r = 0; r < 4; ++r){
      int row = m0 + quad*4 + r;
      u16 hv = f2bf(acc[j][r]);
      if (col < 128)      o.S  [(size_t)row*128 + col]       = hv;
      else if (col < 256) o.P1 [(size_t)row*128 + col - 128] = hv;
      else if (col < 384) o.Pd [(size_t)row*128 + col - 256] = hv;
      else if (col < 400) o.SA [(size_t)row*16  + col - 384] = hv;
      else if (col < 416) o.P1A[(size_t)row*16  + col - 400] = hv;
      else                o.PdA[(size_t)row*16  + col - 416] = hv;
    }
  }
}

// ------- fused CSR gather (half-wave dwordx2) + attention + LN + residual + classifier -------
__global__ __launch_bounds__(256) void k_aggepi(int l,
  const u16* __restrict__ S, const u16* __restrict__ P1,
  const u16* __restrict__ Pd, const u16* __restrict__ SA,
  const u16* __restrict__ P1A, const u16* __restrict__ PdA,
  const int* __restrict__ offO, const int* __restrict__ offI,
  const int* __restrict__ csrO, const int* __restrict__ csrI,
  const float* __restrict__ b_self, const float* __restrict__ b_ctx,
  const float* __restrict__ bsA, const float* __restrict__ bcA,
  const float* __restrict__ att_b1, const float* __restrict__ att_w2,
  const float* __restrict__ gamma, const float* __restrict__ beta,
  const float* __restrict__ flog,
  u16* __restrict__ xb16,
  const float* __restrict__ clsW, const float* __restrict__ clsB,
  float* __restrict__ out)
{
  int n = (blockIdx.x * 256 + threadIdx.x) >> 6;
  int lane = threadIdx.x & 63;
  int f0 = lane * 2;
  // half-wave gather layout: half h handles edges (pair_base + h); sub-lane s
  // covers features 4s..4s+3 (8 bytes at offset 8s of each 256B Pd row)
  int h = lane >> 5, s5 = lane & 31;
  const u16* PdH = Pd + 4*s5;

  int begO = offO[n], endO = offO[n+1];
  int begI = offI[n], endI = offI[n+1];

  float oa0=0.f,oa1=0.f,oa2=0.f,oa3=0.f, ob0=0.f,ob1=0.f,ob2=0.f,ob3=0.f;
  float ia0=0.f,ia1=0.f,ia2=0.f,ia3=0.f, ib0=0.f,ib1=0.f,ib2=0.f,ib3=0.f;

  int eO = begO, eI = begI;
  // fused main loop: 2 O-pairs + 2 I-pairs per iteration (8 row-loads in flight)
  for (; eO + 4 <= endO && eI + 4 <= endI; eO += 4, eI += 4){
    int nO0 = csrO[eO + h],     nO1 = csrO[eO + 2 + h];
    int nI0 = csrI[eI + h],     nI1 = csrI[eI + 2 + h];
    uint2 vO0 = *(const uint2*)(PdH + (size_t)nO0*128);
    uint2 vO1 = *(const uint2*)(PdH + (size_t)nO1*128);
    uint2 vI0 = *(const uint2*)(PdH + (size_t)nI0*128);
    uint2 vI1 = *(const uint2*)(PdH + (size_t)nI1*128);
    oa0 += bflo(vO0.x); oa1 += bfhi(vO0.x); oa2 += bflo(vO0.y); oa3 += bfhi(vO0.y);
    ob0 += bflo(vO1.x); ob1 += bfhi(vO1.x); ob2 += bflo(vO1.y); ob3 += bfhi(vO1.y);
    ia0 += bflo(vI0.x); ia1 += bfhi(vI0.x); ia2 += bflo(vI0.y); ia3 += bfhi(vI0.y);
    ib0 += bflo(vI1.x); ib1 += bfhi(vI1.x); ib2 += bflo(vI1.y); ib3 += bfhi(vI1.y);
  }
  // drain O pairs
  for (; eO + 2 <= endO; eO += 2){
    int nb = csrO[eO + h];
    uint2 v = *(const uint2*)(PdH + (size_t)nb*128);
    oa0 += bflo(v.x); oa1 += bfhi(v.x); oa2 += bflo(v.y); oa3 += bfhi(v.y);
  }
  if (eO < endO && h == 0){   // odd leftover: half 0 only
    int nb = csrO[eO];
    uint2 v = *(const uint2*)(PdH + (size_t)nb*128);
    oa0 += bflo(v.x); oa1 += bfhi(v.x); oa2 += bflo(v.y); oa3 += bfhi(v.y);
  }
  // drain I pairs
  for (; eI + 2 <= endI; eI += 2){
    int nb = csrI[eI + h];
    uint2 v = *(const uint2*)(PdH + (size_t)nb*128);
    ia0 += bflo(v.x); ia1 += bfhi(v.x); ia2 += bflo(v.y); ia3 += bfhi(v.y);
  }
  if (eI < endI && h == 0){
    int nb = csrI[eI];
    uint2 v = *(const uint2*)(PdH + (size_t)nb*128);
    ia0 += bflo(v.x); ia1 += bfhi(v.x); ia2 += bflo(v.y); ia3 += bfhi(v.y);
  }
  oa0 += ob0; oa1 += ob1; oa2 += ob2; oa3 += ob3;
  ia0 += ib0; ia1 += ib1; ia2 += ib2; ia3 += ib3;
  // cross-half combine: full sums for features 4*s5..4*s5+3
  oa0 += __shfl_xor(oa0, 32); oa1 += __shfl_xor(oa1, 32);
  oa2 += __shfl_xor(oa2, 32); oa3 += __shfl_xor(oa3, 32);
  ia0 += __shfl_xor(ia0, 32); ia1 += __shfl_xor(ia1, 32);
  ia2 += __shfl_xor(ia2, 32); ia3 += __shfl_xor(ia3, 32);
  // redistribute to 2-feats/lane: feature 2*lane is at lane>>1, element 2*(lane&1)
  {
    int src = lane >> 1;
    float t0 = __shfl(oa0, src), t1 = __shfl(oa1, src), t2 = __shfl(oa2, src), t3 = __shfl(oa3, src);
    float u0 = __shfl(ia0, src), u1 = __shfl(ia1, src), u2 = __shfl(ia2, src), u3 = __shfl(ia3, src);
    int odd = lane & 1;
    oa0 = odd ? t2 : t0;  oa1 = odd ? t3 : t1;
    ia0 = odd ? u2 : u0;  ia1 = odd ? u3 : u1;
  }
  float ao0 = oa0, ao1 = oa1, ai0 = ia0, ai1 = ia1;

  // --- PdA gathers: 4 edges/iter via the four 16-lane groups, 2x unrolled ---
  int a16 = lane & 15, g = lane >> 4;
  float aoa = 0.f, aoa2 = 0.f, aia = 0.f, aia2 = 0.f;
  {
    int e2 = begO + g;
    for (; e2 + 4 < endO; e2 += 8){
      aoa  += bf2f(PdA[(size_t)csrO[e2]*16 + a16]);
      aoa2 += bf2f(PdA[(size_t)csrO[e2+4]*16 + a16]);
    }
    if (e2 < endO) aoa += bf2f(PdA[(size_t)csrO[e2]*16 + a16]);
    aoa += aoa2;
  }
  {
    int e2 = begI + g;
    for (; e2 + 4 < endI; e2 += 8){
      aia  += bf2f(PdA[(size_t)csrI[e2]*16 + a16]);
      aia2 += bf2f(PdA[(size_t)csrI[e2+4]*16 + a16]);
    }
    if (e2 < endI) aia += bf2f(PdA[(size_t)csrI[e2]*16 + a16]);
    aia += aia2;
  }
  aoa += __shfl_xor(aoa, 16); aoa += __shfl_xor(aoa, 32);
  aia += __shfl_xor(aia, 16); aia += __shfl_xor(aia, 32);

  float dO = (float)(endO - begO), dI = (float)(endI - begI);

  // --- three views, 2 features per lane ---
  u32 sv = *(const u32*)(S  + (size_t)n*128 + f0);
  u32 pv = *(const u32*)(P1 + (size_t)n*128 + f0);
  float2 bsv = *(const float2*)(b_self + l*128 + f0);
  float2 bcv = *(const float2*)(b_ctx  + l*128 + f0);
  float p10 = bflo(pv), p11 = bfhi(pv);
  float mv00 = bflo(sv) + bsv.x;
  float mv01 = bfhi(sv) + bsv.y;
  float mv10 = dO*p10 + ao0 + bcv.x, mv11 = dO*p11 + ao1 + bcv.y;
  float mv20 = dI*p10 + ai0 + bcv.x, mv21 = dI*p11 + ai1 + bcv.y;

  // --- attention: lanes [v*16 + a], v<3 compute tanh(t + b1)*w2, reduce over a ---
  int a = a16, v = g;
  float u = 0.f;
  if (v < 3){
    float t;
    if (v == 0)      t = bf2f(SA[(size_t)n*16 + a]) + bsA[l*16 + a];
    else if (v == 1) t = dO*bf2f(P1A[(size_t)n*16 + a]) + aoa + bcA[l*16 + a];
    else             t = dI*bf2f(P1A[(size_t)n*16 + a]) + aia + bcA[l*16 + a];
    u = tanhf(t + att_b1[l*16 + a]) * att_w2[l*16 + a];
  }
  u += __shfl_xor(u, 1); u += __shfl_xor(u, 2);
  u += __shfl_xor(u, 4); u += __shfl_xor(u, 8);
  float s0 = __shfl(u, 0), s1 = __shfl(u, 16), s2 = __shfl(u, 32);
  float mx = fmaxf(s0, fmaxf(s1, s2));
  float e0 = __expf(s0-mx), e1 = __expf(s1-mx), e2 = __expf(s2-mx);
  float inv = 1.f / (e0 + e1 + e2);
  float w0 = e0*inv, w1 = e1*inv, w2v = e2*inv;
  float h0 = w0*mv00 + w1*mv10 + w2v*mv20;
  float h1 = w0*mv01 + w1*mv11 + w2v*mv21;

  // --- layer norm over 128 ---
  float sum = h0 + h1, sq = h0*h0 + h1*h1;
  #pragma unroll
  for (int m = 1; m < 64; m <<= 1){ sum += __shfl_xor(sum, m); sq += __shfl_xor(sq, m); }
  float mu = sum * (1.f/128.f);
  float var = sq * (1.f/128.f) - mu*mu;
  float rs = rsqrtf(var + LN_EPS);
  float2 gv = *(const float2*)(gamma + l*128 + f0);
  float2 bv = *(const float2*)(beta  + l*128 + f0);
  float y0 = fmaxf((h0 - mu)*rs*gv.x + bv.x, 0.f);
  float y1 = fmaxf((h1 - mu)*rs*gv.y + bv.y, 0.f);
  float xn0 = y0, xn1 = y1;
  if (l > 0){
    u32 xv = *(const u32*)(xb16 + (size_t)n*128 + f0);
    xn0 += bflo(xv); xn1 += bfhi(xv);
  }
  // bf16 residual stream (also next layer's GEMM input)
  *(u32*)(xb16 + (size_t)n*128 + f0) = (u32)f2bf(xn0) | ((u32)f2bf(xn1) << 16);

  // fusion weight (softmax over 4 logits)
  float g0 = flog[0], g1 = flog[1], g2 = flog[2], g3 = flog[3];
  float gm = fmaxf(fmaxf(g0,g1), fmaxf(g2,g3));
  float q0 = __expf(g0-gm), q1 = __expf(g1-gm), q2 = __expf(g2-gm), q3 = __expf(g3-gm);
  float fwl = (l==0?q0 : l==1?q1 : l==2?q2 : q3) / (q0+q1+q2+q3);

  // classifier accumulate: out[n,:] += fwl * (x_l[n] @ clsW); bias at last layer
  float4 w = *(const float4*)(clsW + lane*4);   // rows 2*lane, 2*lane+1 of [128,2]
  float o0 = xn0*w.x + xn1*w.z;
  float o1 = xn0*w.y + xn1*w.w;
  #pragma unroll
  for (int m = 1; m < 64; m <<= 1){ o0 += __shfl_xor(o0, m); o1 += __shfl_xor(o1, m); }
  if (lane == 0){
    float2* op = (float2*)(out + (size_t)n*2);
    float2 prev = (l > 0) ? *op : make_float2(0.f, 0.f);
    float r0 = prev.x + fwl*o0, r1 = prev.y + fwl*o1;
    if (l == LL-1){ r0 += clsB[0]; r1 += clsB[1]; }
    *op = make_float2(r0, r1);
  }
}

extern "C" void kernel_launch(void* const* d_in, const int* in_sizes, int n_in,
                              void* d_out, int out_size, void* d_ws, size_t ws_size,
                              hipStream_t stream){
  const float* X0    = (const float*)d_in[0];
  const int*   EI    = (const int*)d_in[1];
  const float* Wself = (const float*)d_in[2];
  const float* bs    = (const float*)d_in[3];
  const float* Wctx  = (const float*)d_in[4];
  const float* bc    = (const float*)d_in[5];
  const float* A1    = (const float*)d_in[6];
  const float* ab1   = (const float*)d_in[7];
  const float* aw2   = (const float*)d_in[8];
  const float* gam   = (const float*)d_in[9];
  const float* bet   = (const float*)d_in[10];
  const float* flog  = (const float*)d_in[11];
  const float* clsW  = (const float*)d_in[12];
  const float* clsB  = (const float*)d_in[13];
  float* out = (float*)d_out;

  char* wsp = (char*)d_ws;
  size_t o = 0;
  auto alloc = [&](size_t b)->char*{ char* p = wsp + o; o = (o + b + 255) & ~(size_t)255; return p; };
  u16*  xb16  = (u16*) alloc((size_t)N_NODES*128*2);
  u16*  S     = (u16*) alloc((size_t)N_NODES*128*2);
  u16*  P1    = (u16*) alloc((size_t)N_NODES*128*2);
  u16*  Pd    = (u16*) alloc((size_t)N_NODES*128*2);
  u16*  SAb   = (u16*) alloc((size_t)N_NODES*16*2);
  u16*  P1A   = (u16*) alloc((size_t)N_NODES*16*2);
  u16*  PdA   = (u16*) alloc((size_t)N_NODES*16*2);
  u16*  WT    = (u16*) alloc((size_t)LL*NCOLS*128*2);
  float* bsA  = (float*)alloc(LL*16*4);
  float* bcA  = (float*)alloc(LL*16*4);
  int* bsum   = (int*) alloc((size_t)2*SCAN_NB*4);
  int* degO   = (int*) alloc((size_t)N_NODES*4);
  int* degI   = (int*) alloc((size_t)N_NODES*4);
  int* cursO  = (int*) alloc((size_t)N_NODES*4);
  int* cursI  = (int*) alloc((size_t)N_NODES*4);
  int* offO   = (int*) alloc((size_t)(N_NODES+1)*4);
  int* offI   = (int*) alloc((size_t)(N_NODES+1)*4);
  int* csrO   = (int*) alloc((size_t)N_EDGES*4);
  int* csrI   = (int*) alloc((size_t)N_EDGES*4);

  if (ws_size < o){
    k_fail<<<(N_NODES*2+255)/256, 256, 0, stream>>>(out);
    return;
  }

  (void)hipMemsetAsync(degO, 0, (size_t)((char*)offO - (char*)degO), stream);

  k_cvt_hist<<<(N_NODES*DD+255)/256, 256, 0, stream>>>(X0, xb16, EI, degO, degI);
  k_scan1<<<dim3(SCAN_NB,2), SCAN_B, 0, stream>>>(degO, degI, bsum);
  k_scan2<<<1, 64, 0, stream>>>(bsum, offO, offI);
  k_scan3<<<dim3(SCAN_NB,2), SCAN_B, 0, stream>>>(degO, degI, bsum, offO, offI);
  k_scatter<<<(N_EDGES+255)/256, 256, 0, stream>>>(EI, offO, offI, cursO, cursI, csrO, csrI);
  k_pack<<<WT_BLOCKS+1, 256, 0, stream>>>(Wself, Wctx, A1, bs, bc, WT, bsA, bcA);

  GemmOut go{S, P1, Pd, SAb, P1A, PdA};
  const int gemm_blocks = ((N_NODES/16) + 3) / 4;
  for (int l = 0; l < LL; ++l){
    k_gemm<<<gemm_blocks, 256, 0, stream>>>(xb16, WT + (size_t)l*NCOLS*128, go);
    k_aggepi<<<N_NODES/4, 256, 0, stream>>>(l, S, P1, Pd, SAb, P1A, PdA,
                                            offO, offI, csrO, csrI,
                                            bs, bc, bsA, bcA, ab1, aw2,
                                            gam, bet, flog, xb16,
                                            clsW, clsB, out);
  }
}

// Round 12
// 743.995 us; speedup vs baseline: 1.7664x; 1.0332x over previous
//
#include <hip/hip_runtime.h>

#define N_NODES 50000
#define N_EDGES 800000
#define DD 128
#define HH 128
#define LL 4
#define AHH 16
#define LN_EPS 1e-5f
#define NCOLS 432   // 128 S | 128 P1 | 128 Pd | 16 SA | 16 P1A | 16 PdA
#define PDXW 160    // PdX row: 128 Pd + 16 PdA + 16 pad (320B, line-aligned)
#define SCAN_B 512
#define SCAN_NB ((N_NODES + SCAN_B - 1) / SCAN_B)
#define WTPAD 136
#define WT_BLOCKS ((LL*NCOLS*DD)/256)   // 864, exact

typedef unsigned short u16;
typedef unsigned int u32;
typedef __attribute__((ext_vector_type(8))) short short8;
typedef __attribute__((ext_vector_type(4))) float f32x4;

__device__ __forceinline__ float bf2f(u16 h){
  u32 u = ((u32)h) << 16;
  return __builtin_bit_cast(float, u);
}
__device__ __forceinline__ float bflo(u32 v){ return __builtin_bit_cast(float, v << 16); }
__device__ __forceinline__ float bfhi(u32 v){ return __builtin_bit_cast(float, v & 0xffff0000u); }
__device__ __forceinline__ u16 f2bf(float x){
  u32 u = __builtin_bit_cast(u32, x);
  u += 0x7fffu + ((u >> 16) & 1u);
  return (u16)(u >> 16);
}

// ---------------- sentinel (workspace too small) ----------------
__global__ void k_fail(float* out){
  int i = blockIdx.x*256 + threadIdx.x;
  if (i < N_NODES*2) out[i] = 1.0e6f;
}

// ---------------- fused: f32->bf16 conversion + degree histograms ----------------
__global__ __launch_bounds__(256) void k_cvt_hist(const float* __restrict__ X,
    u16* __restrict__ Xb, const int* __restrict__ ei, int* degO, int* degI){
  int i = blockIdx.x*256 + threadIdx.x;
  if (i < N_NODES*DD) Xb[i] = f2bf(X[i]);
  if (i < N_EDGES){
    atomicAdd(&degO[ei[N_EDGES + i]], 1);  // tgt histogram (outgoing view)
    atomicAdd(&degI[ei[i]], 1);            // src histogram (incoming view)
  }
}

// 3-phase parallel exclusive scan
__global__ __launch_bounds__(SCAN_B) void k_scan1(const int* __restrict__ degO,
                                                  const int* __restrict__ degI, int* bsum){
  int b = blockIdx.x, t = threadIdx.x;
  const int* deg = blockIdx.y ? degI : degO;
  int i = b*SCAN_B + t;
  int v = (i < N_NODES) ? deg[i] : 0;
  #pragma unroll
  for (int m = 1; m < 64; m <<= 1) v += __shfl_xor(v, m);
  __shared__ int ws[SCAN_B/64];
  if ((t & 63) == 0) ws[t >> 6] = v;
  __syncthreads();
  if (t == 0){
    int s = 0;
    for (int w = 0; w < SCAN_B/64; ++w) s += ws[w];
    bsum[blockIdx.y*SCAN_NB + b] = s;
  }
}
__global__ void k_scan2(int* bsum, int* offO, int* offI){
  if (threadIdx.x == 0){
    int run = 0;
    for (int i = 0; i < SCAN_NB; ++i){ int v = bsum[i]; bsum[i] = run; run += v; }
    offO[N_NODES] = run;
    run = 0;
    for (int i = 0; i < SCAN_NB; ++i){ int v = bsum[SCAN_NB+i]; bsum[SCAN_NB+i] = run; run += v; }
    offI[N_NODES] = run;
  }
}
__global__ __launch_bounds__(SCAN_B) void k_scan3(const int* __restrict__ degO,
                                                  const int* __restrict__ degI,
                                                  const int* __restrict__ bsum,
                                                  int* offO, int* offI){
  int b = blockIdx.x, t = threadIdx.x, lane = t & 63, w = t >> 6;
  const int* deg = blockIdx.y ? degI : degO;
  int* off = blockIdx.y ? offI : offO;
  int i = b*SCAN_B + t;
  int v = (i < N_NODES) ? deg[i] : 0;
  int x = v;
  #pragma unroll
  for (int m = 1; m < 64; m <<= 1){ int tt = __shfl_up(x, m); if (lane >= m) x += tt; }
  __shared__ int ws[SCAN_B/64];
  if (lane == 63) ws[w] = x;
  __syncthreads();
  int woff = 0;
  for (int k = 0; k < w; ++k) woff += ws[k];
  if (i < N_NODES) off[i] = bsum[blockIdx.y*SCAN_NB + b] + woff + x - v;
}

__global__ void k_scatter(const int* __restrict__ ei, const int* __restrict__ offO,
                          const int* __restrict__ offI, int* cursO, int* cursI,
                          int* csrO, int* csrI){
  int e = blockIdx.x*256 + threadIdx.x;
  if (e >= N_EDGES) return;
  int s = ei[e], t = ei[N_EDGES + e];
  int p = atomicAdd(&cursO[t], 1); csrO[offO[t] + p] = s;
  int q = atomicAdd(&cursI[s], 1); csrI[offI[s] + q] = t;
}

// ---------------- fused weight+bias packing (f32 sources -> bf16 WT, f32 bsA/bcA) ----------------
__global__ void k_pack(const float* __restrict__ Wself, const float* __restrict__ Wctx,
                       const float* __restrict__ A1, const float* __restrict__ bs,
                       const float* __restrict__ bc, u16* __restrict__ WT,
                       float* bsA, float* bcA){
  if (blockIdx.x == WT_BLOCKS){
    int i = threadIdx.x;
    if (i < LL*2*AHH){
      int l = i >> 5, which = (i >> 4) & 1, a = i & 15;
      const float* b = which ? (bc + l*HH) : (bs + l*HH);
      const float* A = A1 + (size_t)l*HH*AHH;
      float v = 0.f;
      for (int h = 0; h < HH; ++h) v += b[h] * A[h*AHH + a];
      (which ? bcA : bsA)[l*AHH + a] = v;
    }
    return;
  }
  int idx = blockIdx.x*256 + threadIdx.x;
  int k = idx & 127;
  int j = (idx >> 7) % NCOLS;
  int l = idx / (NCOLS*DD);
  const float* Ws = Wself + (size_t)l*DD*HH;
  const float* Wc = Wctx + (size_t)l*2*DD*HH;
  const float* A  = A1 + (size_t)l*HH*AHH;
  float v = 0.f;
  if (j < 128) v = Ws[k*HH + j];
  else if (j < 256) v = Wc[k*HH + (j-128)];
  else if (j < 384) v = Wc[(128+k)*HH + (j-256)] - Wc[k*HH + (j-256)];
  else if (j < 400){ int a = j-384; for (int h=0; h<HH; ++h) v += Ws[k*HH+h] * A[h*AHH+a]; }
  else if (j < 416){ int a = j-400; for (int h=0; h<HH; ++h) v += Wc[k*HH+h] * A[h*AHH+a]; }
  else { int a = j-416; for (int h=0; h<HH; ++h) v += (Wc[(128+k)*HH+h] - Wc[k*HH+h]) * A[h*AHH+a]; }
  WT[((size_t)l*NCOLS + j)*DD + k] = f2bf(v);
}

// ---------------- fused GEMM: 3-tile LDS staging, 9 stages ----------------
struct GemmOut { u16 *S, *P1, *PdX, *SA, *P1A; };

__global__ __launch_bounds__(256) void k_gemm(const u16* __restrict__ X,
                                              const u16* __restrict__ WT, GemmOut o){
  __shared__ u16 lw[3*16*WTPAD];
  int tid = threadIdx.x;
  int wid = tid >> 6, lane = tid & 63;
  int m0 = (blockIdx.x*4 + wid)*16;
  bool mvalid = (m0 < N_NODES);
  int m0c = mvalid ? m0 : (N_NODES - 16);
  int l15 = lane & 15, quad = lane >> 4;
  int sr = tid >> 4, sp = tid & 15;

  f32x4 acc[27];
  #pragma unroll
  for (int j = 0; j < 27; ++j) acc[j] = (f32x4){0.f,0.f,0.f,0.f};

  const u16* xr = X + (size_t)(m0c + l15)*DD + quad*8;
  short8 a[4];
  #pragma unroll
  for (int ks = 0; ks < 4; ++ks) a[ks] = *(const short8*)(xr + ks*32);

  short8 st[3];
  #pragma unroll
  for (int k = 0; k < 3; ++k)
    st[k] = *(const short8*)(WT + ((size_t)k*16 + sr)*DD + sp*8);

  for (int stage = 0; stage < 9; ++stage){
    int jbase = stage*3;
    __syncthreads();
    #pragma unroll
    for (int k = 0; k < 3; ++k)
      *(short8*)(&lw[(k*16 + sr)*WTPAD + sp*8]) = st[k];
    __syncthreads();
    if (stage < 8){
      #pragma unroll
      for (int k = 0; k < 3; ++k)
        st[k] = *(const short8*)(WT + ((size_t)(jbase+3+k)*16 + sr)*DD + sp*8);
    }
    #pragma unroll
    for (int k = 0; k < 3; ++k){
      const u16* wb = &lw[(k*16 + l15)*WTPAD + quad*8];
      #pragma unroll
      for (int ks = 0; ks < 4; ++ks){
        short8 b = *(const short8*)(wb + ks*32);
        acc[jbase+k] = __builtin_amdgcn_mfma_f32_16x16x32_bf16(a[ks], b, acc[jbase+k], 0, 0, 0);
      }
    }
  }
  if (!mvalid) return;
  #pragma unroll
  for (int j = 0; j < 27; ++j){
    int col = j*16 + l15;
    #pragma unroll
    for (int r = 0; r < 4; ++r){
      int row = m0 + quad*4 + r;
      u16 hv = f2bf(acc[j][r]);
      if (col < 128)      o.S  [(size_t)row*128 + col]        = hv;
      else if (col < 256) o.P1 [(size_t)row*128 + col - 128]  = hv;
      else if (col < 384) o.PdX[(size_t)row*PDXW + col - 256] = hv;
      else if (col < 400) o.SA [(size_t)row*16  + col - 384]  = hv;
      else if (col < 416) o.P1A[(size_t)row*16  + col - 400]  = hv;
      else                o.PdX[(size_t)row*PDXW + 128 + (col - 416)] = hv;
    }
  }
}

// ------- fused CSR gather (single pass over PdX rows: Pd + PdA together) -------
__global__ __launch_bounds__(256) void k_aggepi(int l,
  const u16* __restrict__ S, const u16* __restrict__ P1,
  const u16* __restrict__ PdX, const u16* __restrict__ SA,
  const u16* __restrict__ P1A,
  const int* __restrict__ offO, const int* __restrict__ offI,
  const int* __restrict__ csrO, const int* __restrict__ csrI,
  const float* __restrict__ b_self, const float* __restrict__ b_ctx,
  const float* __restrict__ bsA, const float* __restrict__ bcA,
  const float* __restrict__ att_b1, const float* __restrict__ att_w2,
  const float* __restrict__ gamma, const float* __restrict__ beta,
  const float* __restrict__ flog,
  u16* __restrict__ xb16,
  const float* __restrict__ clsW, const float* __restrict__ clsB,
  float* __restrict__ out)
{
  int n = (blockIdx.x * 256 + threadIdx.x) >> 6;
  int lane = threadIdx.x & 63;
  int f0 = lane * 2;
  const u16* PdF  = PdX + f0;                    // main: u32 @ PdF + nb*PDXW (2 feats/lane)
  const u16* PdAF = PdX + 128 + (lane & 7)*2;    // aux: u32 @ PdAF + nb*PDXW (PdA pair, replicated x8)

  int begO = offO[n], endO = offO[n+1];
  int begI = offI[n], endI = offI[n+1];

  float o00=0.f,o01=0.f,o10=0.f,o11=0.f,o20=0.f,o21=0.f,o30=0.f,o31=0.f;
  float i00=0.f,i01=0.f,i10=0.f,i11=0.f,i20=0.f,i21=0.f,i30=0.f,i31=0.f;
  float poa0=0.f, poa1=0.f, pia0=0.f, pia1=0.f;  // PdA pair sums (feat 2p, 2p+1), p = lane&7

  int eO = begO, eI = begI;
  // alignment heads (csr bases 256B-aligned)
  for (; eO < endO && (eO & 3); ++eO){
    size_t rb = (size_t)csrO[eO]*PDXW;
    u32 v = *(const u32*)(PdF + rb);
    u32 p = *(const u32*)(PdAF + rb);
    o00 += bflo(v); o01 += bfhi(v);
    poa0 += bflo(p); poa1 += bfhi(p);
  }
  for (; eI < endI && (eI & 3); ++eI){
    size_t rb = (size_t)csrI[eI]*PDXW;
    u32 v = *(const u32*)(PdF + rb);
    u32 p = *(const u32*)(PdAF + rb);
    i00 += bflo(v); i01 += bfhi(v);
    pia0 += bflo(p); pia1 += bfhi(p);
  }
  // fused main loop: 4 O + 4 I rows (+aux) in flight, int4 index loads
  for (; eO + 4 <= endO && eI + 4 <= endI; eO += 4, eI += 4){
    int4 nO = *(const int4*)(csrO + eO);
    int4 nI = *(const int4*)(csrI + eI);
    size_t rO0 = (size_t)nO.x*PDXW, rO1 = (size_t)nO.y*PDXW, rO2 = (size_t)nO.z*PDXW, rO3 = (size_t)nO.w*PDXW;
    size_t rI0 = (size_t)nI.x*PDXW, rI1 = (size_t)nI.y*PDXW, rI2 = (size_t)nI.z*PDXW, rI3 = (size_t)nI.w*PDXW;
    u32 a0 = *(const u32*)(PdF + rO0);
    u32 a1 = *(const u32*)(PdF + rO1);
    u32 a2 = *(const u32*)(PdF + rO2);
    u32 a3 = *(const u32*)(PdF + rO3);
    u32 b0 = *(const u32*)(PdF + rI0);
    u32 b1 = *(const u32*)(PdF + rI1);
    u32 b2 = *(const u32*)(PdF + rI2);
    u32 b3 = *(const u32*)(PdF + rI3);
    u32 pa0 = *(const u32*)(PdAF + rO0);
    u32 pa1 = *(const u32*)(PdAF + rO1);
    u32 pa2 = *(const u32*)(PdAF + rO2);
    u32 pa3 = *(const u32*)(PdAF + rO3);
    u32 pb0 = *(const u32*)(PdAF + rI0);
    u32 pb1 = *(const u32*)(PdAF + rI1);
    u32 pb2 = *(const u32*)(PdAF + rI2);
    u32 pb3 = *(const u32*)(PdAF + rI3);
    o00 += bflo(a0); o01 += bfhi(a0);
    o10 += bflo(a1); o11 += bfhi(a1);
    o20 += bflo(a2); o21 += bfhi(a2);
    o30 += bflo(a3); o31 += bfhi(a3);
    i00 += bflo(b0); i01 += bfhi(b0);
    i10 += bflo(b1); i11 += bfhi(b1);
    i20 += bflo(b2); i21 += bfhi(b2);
    i30 += bflo(b3); i31 += bfhi(b3);
    poa0 += bflo(pa0) + bflo(pa1) + bflo(pa2) + bflo(pa3);
    poa1 += bfhi(pa0) + bfhi(pa1) + bfhi(pa2) + bfhi(pa3);
    pia0 += bflo(pb0) + bflo(pb1) + bflo(pb2) + bflo(pb3);
    pia1 += bfhi(pb0) + bfhi(pb1) + bfhi(pb2) + bfhi(pb3);
  }
  // drain O
  for (; eO + 4 <= endO; eO += 4){
    int4 nO = *(const int4*)(csrO + eO);
    size_t rO0 = (size_t)nO.x*PDXW, rO1 = (size_t)nO.y*PDXW, rO2 = (size_t)nO.z*PDXW, rO3 = (size_t)nO.w*PDXW;
    u32 a0 = *(const u32*)(PdF + rO0);
    u32 a1 = *(const u32*)(PdF + rO1);
    u32 a2 = *(const u32*)(PdF + rO2);
    u32 a3 = *(const u32*)(PdF + rO3);
    u32 pa0 = *(const u32*)(PdAF + rO0);
    u32 pa1 = *(const u32*)(PdAF + rO1);
    u32 pa2 = *(const u32*)(PdAF + rO2);
    u32 pa3 = *(const u32*)(PdAF + rO3);
    o00 += bflo(a0); o01 += bfhi(a0);
    o10 += bflo(a1); o11 += bfhi(a1);
    o20 += bflo(a2); o21 += bfhi(a2);
    o30 += bflo(a3); o31 += bfhi(a3);
    poa0 += bflo(pa0) + bflo(pa1) + bflo(pa2) + bflo(pa3);
    poa1 += bfhi(pa0) + bfhi(pa1) + bfhi(pa2) + bfhi(pa3);
  }
  for (; eO < endO; ++eO){
    size_t rb = (size_t)csrO[eO]*PDXW;
    u32 v = *(const u32*)(PdF + rb);
    u32 p = *(const u32*)(PdAF + rb);
    o00 += bflo(v); o01 += bfhi(v);
    poa0 += bflo(p); poa1 += bfhi(p);
  }
  // drain I
  for (; eI + 4 <= endI; eI += 4){
    int4 nI = *(const int4*)(csrI + eI);
    size_t rI0 = (size_t)nI.x*PDXW, rI1 = (size_t)nI.y*PDXW, rI2 = (size_t)nI.z*PDXW, rI3 = (size_t)nI.w*PDXW;
    u32 b0 = *(const u32*)(PdF + rI0);
    u32 b1 = *(const u32*)(PdF + rI1);
    u32 b2 = *(const u32*)(PdF + rI2);
    u32 b3 = *(const u32*)(PdF + rI3);
    u32 pb0 = *(const u32*)(PdAF + rI0);
    u32 pb1 = *(const u32*)(PdAF + rI1);
    u32 pb2 = *(const u32*)(PdAF + rI2);
    u32 pb3 = *(const u32*)(PdAF + rI3);
    i00 += bflo(b0); i01 += bfhi(b0);
    i10 += bflo(b1); i11 += bfhi(b1);
    i20 += bflo(b2); i21 += bfhi(b2);
    i30 += bflo(b3); i31 += bfhi(b3);
    pia0 += bflo(pb0) + bflo(pb1) + bflo(pb2) + bflo(pb3);
    pia1 += bfhi(pb0) + bfhi(pb1) + bfhi(pb2) + bfhi(pb3);
  }
  for (; eI < endI; ++eI){
    size_t rb = (size_t)csrI[eI]*PDXW;
    u32 v = *(const u32*)(PdF + rb);
    u32 p = *(const u32*)(PdAF + rb);
    i00 += bflo(v); i01 += bfhi(v);
    pia0 += bflo(p); pia1 += bfhi(p);
  }
  float ao0 = (o00+o10)+(o20+o30), ao1 = (o01+o11)+(o21+o31);
  float ai0 = (i00+i10)+(i20+i30), ai1 = (i01+i11)+(i21+i31);

  // PdA sums: lane k holds pair (k&7) = feats 2(k&7), 2(k&7)+1 — replicated 8x.
  // Attention lane wants feat a16: pair a16>>1 (lane a16>>1), element a16&1.
  int a16 = lane & 15, g = lane >> 4;
  float aoa, aia;
  {
    int p = a16 >> 1;
    float t0 = __shfl(poa0, p), t1 = __shfl(poa1, p);
    float u0 = __shfl(pia0, p), u1 = __shfl(pia1, p);
    int odd = a16 & 1;
    aoa = odd ? t1 : t0;
    aia = odd ? u1 : u0;
  }

  float dO = (float)(endO - begO), dI = (float)(endI - begI);

  // --- three views, 2 features per lane ---
  u32 sv = *(const u32*)(S  + (size_t)n*128 + f0);
  u32 pv = *(const u32*)(P1 + (size_t)n*128 + f0);
  float2 bsv = *(const float2*)(b_self + l*128 + f0);
  float2 bcv = *(const float2*)(b_ctx  + l*128 + f0);
  float p10 = bflo(pv), p11 = bfhi(pv);
  float mv00 = bflo(sv) + bsv.x;
  float mv01 = bfhi(sv) + bsv.y;
  float mv10 = dO*p10 + ao0 + bcv.x, mv11 = dO*p11 + ao1 + bcv.y;
  float mv20 = dI*p10 + ai0 + bcv.x, mv21 = dI*p11 + ai1 + bcv.y;

  // --- attention: lanes [v*16 + a], v<3 compute tanh(t + b1)*w2, reduce over a ---
  int a = a16, v = g;
  float u = 0.f;
  if (v < 3){
    float t;
    if (v == 0)      t = bf2f(SA[(size_t)n*16 + a]) + bsA[l*16 + a];
    else if (v == 1) t = dO*bf2f(P1A[(size_t)n*16 + a]) + aoa + bcA[l*16 + a];
    else             t = dI*bf2f(P1A[(size_t)n*16 + a]) + aia + bcA[l*16 + a];
    u = tanhf(t + att_b1[l*16 + a]) * att_w2[l*16 + a];
  }
  u += __shfl_xor(u, 1); u += __shfl_xor(u, 2);
  u += __shfl_xor(u, 4); u += __shfl_xor(u, 8);
  float s0 = __shfl(u, 0), s1 = __shfl(u, 16), s2 = __shfl(u, 32);
  float mx = fmaxf(s0, fmaxf(s1, s2));
  float e0 = __expf(s0-mx), e1 = __expf(s1-mx), e2 = __expf(s2-mx);
  float inv = 1.f / (e0 + e1 + e2);
  float w0 = e0*inv, w1 = e1*inv, w2v = e2*inv;
  float h0 = w0*mv00 + w1*mv10 + w2v*mv20;
  float h1 = w0*mv01 + w1*mv11 + w2v*mv21;

  // --- layer norm over 128 ---
  float sum = h0 + h1, sq = h0*h0 + h1*h1;
  #pragma unroll
  for (int m = 1; m < 64; m <<= 1){ sum += __shfl_xor(sum, m); sq += __shfl_xor(sq, m); }
  float mu = sum * (1.f/128.f);
  float var = sq * (1.f/128.f) - mu*mu;
  float rs = rsqrtf(var + LN_EPS);
  float2 gv = *(const float2*)(gamma + l*128 + f0);
  float2 bv = *(const float2*)(beta  + l*128 + f0);
  float y0 = fmaxf((h0 - mu)*rs*gv.x + bv.x, 0.f);
  float y1 = fmaxf((h1 - mu)*rs*gv.y + bv.y, 0.f);
  float xn0 = y0, xn1 = y1;
  if (l > 0){
    u32 xv = *(const u32*)(xb16 + (size_t)n*128 + f0);
    xn0 += bflo(xv); xn1 += bfhi(xv);
  }
  *(u32*)(xb16 + (size_t)n*128 + f0) = (u32)f2bf(xn0) | ((u32)f2bf(xn1) << 16);

  // fusion weight (softmax over 4 logits)
  float g0 = flog[0], g1 = flog[1], g2 = flog[2], g3 = flog[3];
  float gm = fmaxf(fmaxf(g0,g1), fmaxf(g2,g3));
  float q0 = __expf(g0-gm), q1 = __expf(g1-gm), q2 = __expf(g2-gm), q3 = __expf(g3-gm);
  float fwl = (l==0?q0 : l==1?q1 : l==2?q2 : q3) / (q0+q1+q2+q3);

  // classifier accumulate
  float4 w = *(const float4*)(clsW + lane*4);
  float o0 = xn0*w.x + xn1*w.z;
  float o1 = xn0*w.y + xn1*w.w;
  #pragma unroll
  for (int m = 1; m < 64; m <<= 1){ o0 += __shfl_xor(o0, m); o1 += __shfl_xor(o1, m); }
  if (lane == 0){
    float2* op = (float2*)(out + (size_t)n*2);
    float2 prev = (l > 0) ? *op : make_float2(0.f, 0.f);
    float r0 = prev.x + fwl*o0, r1 = prev.y + fwl*o1;
    if (l == LL-1){ r0 += clsB[0]; r1 += clsB[1]; }
    *op = make_float2(r0, r1);
  }
}

extern "C" void kernel_launch(void* const* d_in, const int* in_sizes, int n_in,
                              void* d_out, int out_size, void* d_ws, size_t ws_size,
                              hipStream_t stream){
  const float* X0    = (const float*)d_in[0];
  const int*   EI    = (const int*)d_in[1];
  const float* Wself = (const float*)d_in[2];
  const float* bs    = (const float*)d_in[3];
  const float* Wctx  = (const float*)d_in[4];
  const float* bc    = (const float*)d_in[5];
  const float* A1    = (const float*)d_in[6];
  const float* ab1   = (const float*)d_in[7];
  const float* aw2   = (const float*)d_in[8];
  const float* gam   = (const float*)d_in[9];
  const float* bet   = (const float*)d_in[10];
  const float* flog  = (const float*)d_in[11];
  const float* clsW  = (const float*)d_in[12];
  const float* clsB  = (const float*)d_in[13];
  float* out = (float*)d_out;

  char* wsp = (char*)d_ws;
  size_t o = 0;
  auto alloc = [&](size_t b)->char*{ char* p = wsp + o; o = (o + b + 255) & ~(size_t)255; return p; };
  u16*  xb16  = (u16*) alloc((size_t)N_NODES*128*2);
  u16*  S     = (u16*) alloc((size_t)N_NODES*128*2);
  u16*  P1    = (u16*) alloc((size_t)N_NODES*128*2);
  u16*  PdX   = (u16*) alloc((size_t)N_NODES*PDXW*2);
  u16*  SAb   = (u16*) alloc((size_t)N_NODES*16*2);
  u16*  P1A   = (u16*) alloc((size_t)N_NODES*16*2);
  u16*  WT    = (u16*) alloc((size_t)LL*NCOLS*128*2);
  float* bsA  = (float*)alloc(LL*16*4);
  float* bcA  = (float*)alloc(LL*16*4);
  int* bsum   = (int*) alloc((size_t)2*SCAN_NB*4);
  int* degO   = (int*) alloc((size_t)N_NODES*4);
  int* degI   = (int*) alloc((size_t)N_NODES*4);
  int* cursO  = (int*) alloc((size_t)N_NODES*4);
  int* cursI  = (int*) alloc((size_t)N_NODES*4);
  int* offO   = (int*) alloc((size_t)(N_NODES+1)*4);
  int* offI   = (int*) alloc((size_t)(N_NODES+1)*4);
  int* csrO   = (int*) alloc((size_t)N_EDGES*4);
  int* csrI   = (int*) alloc((size_t)N_EDGES*4);

  if (ws_size < o){
    k_fail<<<(N_NODES*2+255)/256, 256, 0, stream>>>(out);
    return;
  }

  (void)hipMemsetAsync(degO, 0, (size_t)((char*)offO - (char*)degO), stream);

  k_cvt_hist<<<(N_NODES*DD+255)/256, 256, 0, stream>>>(X0, xb16, EI, degO, degI);
  k_scan1<<<dim3(SCAN_NB,2), SCAN_B, 0, stream>>>(degO, degI, bsum);
  k_scan2<<<1, 64, 0, stream>>>(bsum, offO, offI);
  k_scan3<<<dim3(SCAN_NB,2), SCAN_B, 0, stream>>>(degO, degI, bsum, offO, offI);
  k_scatter<<<(N_EDGES+255)/256, 256, 0, stream>>>(EI, offO, offI, cursO, cursI, csrO, csrI);
  k_pack<<<WT_BLOCKS+1, 256, 0, stream>>>(Wself, Wctx, A1, bs, bc, WT, bsA, bcA);

  GemmOut go{S, P1, PdX, SAb, P1A};
  const int gemm_blocks = ((N_NODES/16) + 3) / 4;
  for (int l = 0; l < LL; ++l){
    k_gemm<<<gemm_blocks, 256, 0, stream>>>(xb16, WT + (size_t)l*NCOLS*128, go);
    k_aggepi<<<N_NODES/4, 256, 0, stream>>>(l, S, P1, PdX, SAb, P1A,
                                            offO, offI, csrO, csrI,
                                            bs, bc, bsA, bcA, ab1, aw2,
                                            gam, bet, flog, xb16,
                                            clsW, clsB, out);
  }
}